// Round 2
// baseline (1445.639 us; speedup 1.0000x reference)
//
#include <hip/hip_runtime.h>
#include <hip/hip_bf16.h>

#define BB 2
#define SS 4096
#define DD 1024
#define HH 16
#define WW 256
#define FF 4096
#define HDIM 64
#define NBLK (SS / WW)       /* 16 */
#define MROWS (BB * SS)      /* 8192 */

typedef short bfrag8 __attribute__((ext_vector_type(8)));
typedef float floatx4 __attribute__((ext_vector_type(4)));

__device__ __forceinline__ float bf2f(ushort u) {
    union { uint i; float f; } c; c.i = ((uint)u) << 16; return c.f;
}
__device__ __forceinline__ ushort f2bf(float f) {
    union { float f; uint i; } c; c.f = f;
    uint r = (c.i + 0x7FFFu + ((c.i >> 16) & 1u)) >> 16;
    return (ushort)r;
}
__device__ __forceinline__ float gelu_tanh(float x) {
    float x3 = x * x * x;
    return 0.5f * x * (1.f + tanhf(0.7978845608028654f * (x + 0.044715f * x3)));
}

// ---------------------------------------------------------------------------
// f32 -> bf16 bulk convert (n divisible by 1024; grid = n/1024)
// ---------------------------------------------------------------------------
__global__ __launch_bounds__(256) void cvt_f32_bf16(
    const float* __restrict__ in, ushort* __restrict__ out)
{
    size_t i = ((size_t)blockIdx.x * 256 + threadIdx.x) * 4;
    float4 v = *(const float4*)(in + i);
    union { ushort u[4]; uint2 d; } t;
    t.u[0] = f2bf(v.x); t.u[1] = f2bf(v.y);
    t.u[2] = f2bf(v.z); t.u[3] = f2bf(v.w);
    *(uint2*)(out + i) = t.d;
}

// ---------------------------------------------------------------------------
// GEMM: C[M,N] = A[M,K] @ B[K,N] + bias[N]
// A: f32 or bf16 (templated), B: bf16, bias: f32, C: bf16, fp32 accumulate.
// 128x128 tile / block, 4 waves each computing 64x64 via 4x4 MFMA 16x16x32.
// act: 0 = none, 1 = gelu(tanh)
// ---------------------------------------------------------------------------
template <typename AT>
__global__ __launch_bounds__(256) void gemm_bias(
    const AT* __restrict__ A, const ushort* __restrict__ Bm,
    const float* __restrict__ bias, ushort* __restrict__ C,
    int M, int N, int K, int act)
{
    __shared__ ushort sA[128][40];   // [m][k], padded stride 40
    __shared__ ushort sB[128][40];   // [n][k] (transposed), padded

    const int tid  = threadIdx.x;
    const int m0   = blockIdx.y * 128;
    const int n0   = blockIdx.x * 128;
    const int wave = tid >> 6;
    const int lane = tid & 63;
    const int wm   = (wave >> 1) * 64;
    const int wn   = (wave & 1) * 64;
    const int lrow = lane & 15;
    const int quad = lane >> 4;

    floatx4 acc[4][4];
#pragma unroll
    for (int i = 0; i < 4; ++i)
#pragma unroll
        for (int j = 0; j < 4; ++j)
            acc[i][j] = (floatx4){0.f, 0.f, 0.f, 0.f};

    for (int k0 = 0; k0 < K; k0 += 32) {
        // ---- stage A tile 128x32 -> bf16 LDS
        if constexpr (sizeof(AT) == 4) {
            // f32 source: 4 iters of float4 (4 elems) per thread
#pragma unroll
            for (int it = 0; it < 4; ++it) {
                int c   = tid + it * 256;           // 0..1023 chunks of 4
                int row = c >> 3;
                int col = (c & 7) << 2;
                float4 v = *(const float4*)((const float*)A + (size_t)(m0 + row) * K + k0 + col);
                union { ushort u[4]; uint2 d; } t;
                t.u[0] = f2bf(v.x); t.u[1] = f2bf(v.y);
                t.u[2] = f2bf(v.z); t.u[3] = f2bf(v.w);
                *(uint2*)&sA[row][col] = t.d;
            }
        } else {
            // bf16 source: 2 iters of uint4 (8 elems) per thread
#pragma unroll
            for (int it = 0; it < 2; ++it) {
                int c   = tid + it * 256;           // 0..511 chunks of 8
                int row = c >> 2;
                int col = (c & 3) << 3;
                *(uint4*)&sA[row][col] =
                    *(const uint4*)((const ushort*)A + (size_t)(m0 + row) * K + k0 + col);
            }
        }
        // ---- stage B tile 32x128 transposed -> sB[n][k] (bf16 source)
#pragma unroll
        for (int it = 0; it < 2; ++it) {
            int c  = tid + it * 256;
            int nn = c & 127;
            int kg = (c >> 7) << 3;             // 0,8,16,24
            const ushort* src = Bm + (size_t)(k0 + kg) * N + n0 + nn;
            union { ushort u[8]; uint4 v; } t;
#pragma unroll
            for (int j = 0; j < 8; ++j) t.u[j] = src[(size_t)j * N];
            *(uint4*)&sB[nn][kg] = t.v;
        }
        __syncthreads();

        bfrag8 af[4], bfv[4];
#pragma unroll
        for (int mt = 0; mt < 4; ++mt)
            af[mt] = *(const bfrag8*)&sA[wm + mt * 16 + lrow][quad << 3];
#pragma unroll
        for (int nt = 0; nt < 4; ++nt)
            bfv[nt] = *(const bfrag8*)&sB[wn + nt * 16 + lrow][quad << 3];
#pragma unroll
        for (int mt = 0; mt < 4; ++mt)
#pragma unroll
            for (int nt = 0; nt < 4; ++nt)
                acc[mt][nt] = __builtin_amdgcn_mfma_f32_16x16x32_bf16(
                    af[mt], bfv[nt], acc[mt][nt], 0, 0, 0);
        __syncthreads();
    }

    // epilogue: C/D layout col = lane&15, row = quad*4 + reg
#pragma unroll
    for (int nt = 0; nt < 4; ++nt) {
        int col = n0 + wn + nt * 16 + lrow;
        float bb = bias[col];
#pragma unroll
        for (int mt = 0; mt < 4; ++mt) {
#pragma unroll
            for (int r = 0; r < 4; ++r) {
                int row = m0 + wm + mt * 16 + (quad << 2) + r;
                float v = acc[mt][nt][r] + bb;
                if (act) v = gelu_tanh(v);
                C[(size_t)row * N + col] = f2bf(v);
            }
        }
    }
}

// ---------------------------------------------------------------------------
// Sliding-window attention. Block = (block n, head h, batch b); 256 threads,
// one query row each. K/V chunks (prev/self/next) staged in LDS (bf16),
// per-thread online softmax over the banded key range |qpos-kpos| <= W.
// q/k/v/out are bf16 [B,S,H,HD] flattened as [B,S,D].
// ---------------------------------------------------------------------------
__global__ __launch_bounds__(256) void attn_kernel(
    const ushort* __restrict__ q, const ushort* __restrict__ k,
    const ushort* __restrict__ v, ushort* __restrict__ out)
{
    __shared__ ushort sK[256][72];
    __shared__ ushort sV[256][72];

    const int n = blockIdx.x, h = blockIdx.y, b = blockIdx.z;
    const int tid = threadIdx.x;
    const int qg  = n * WW + tid;
    const size_t qoff = ((size_t)(b * SS + qg)) * DD + h * HDIM;

    float qr[64];
#pragma unroll
    for (int j = 0; j < 8; ++j) {
        union { uint4 v4; ushort u[8]; } t;
        t.v4 = *(const uint4*)(q + qoff + j * 8);
#pragma unroll
        for (int e = 0; e < 8; ++e) qr[j * 8 + e] = bf2f(t.u[e]);
    }

    float mrun = -1e30f, lrun = 0.f;
    float o[64];
#pragma unroll
    for (int d = 0; d < 64; ++d) o[d] = 0.f;
    const float scale = 0.125f;  // 1/sqrt(64)

    for (int c = n - 1; c <= n + 1; ++c) {
        if (c < 0 || c >= NBLK) continue;     // block-uniform skip
        __syncthreads();
        {
            size_t koff = ((size_t)(b * SS + c * WW + tid)) * DD + h * HDIM;
#pragma unroll
            for (int j = 0; j < 8; ++j) {
                *(uint4*)&sK[tid][j * 8] = *(const uint4*)(k + koff + j * 8);
                *(uint4*)&sV[tid][j * 8] = *(const uint4*)(v + koff + j * 8);
            }
        }
        __syncthreads();

        // banded range within this chunk (masked keys -> exp underflows to 0
        // in the reference too, so skipping them is exact)
        int lo, hi;
        if (c == n)      { lo = 0;   hi = 255; }
        else if (c < n)  { lo = tid; hi = 255; }
        else             { lo = 0;   hi = tid; }

        for (int j = lo; j <= hi; ++j) {
            float s = 0.f;
#pragma unroll
            for (int d8 = 0; d8 < 8; ++d8) {
                union { uint4 v4; ushort u[8]; } t;
                t.v4 = *(const uint4*)&sK[j][d8 * 8];
#pragma unroll
                for (int e = 0; e < 8; ++e) s += qr[d8 * 8 + e] * bf2f(t.u[e]);
            }
            s *= scale;
            float mn = fmaxf(mrun, s);
            float alpha = __expf(mrun - mn);   // 0 on first key (mrun=-1e30)
            float p     = __expf(s - mn);
            lrun = lrun * alpha + p;
            mrun = mn;
#pragma unroll
            for (int d8 = 0; d8 < 8; ++d8) {
                union { uint4 v4; ushort u[8]; } t;
                t.v4 = *(const uint4*)&sV[j][d8 * 8];
#pragma unroll
                for (int e = 0; e < 8; ++e)
                    o[d8 * 8 + e] = o[d8 * 8 + e] * alpha + p * bf2f(t.u[e]);
            }
        }
    }

    float inv = 1.f / lrun;
#pragma unroll
    for (int j = 0; j < 8; ++j) {
        union { uint4 v4; ushort u[8]; } t;
#pragma unroll
        for (int e = 0; e < 8; ++e) t.u[e] = f2bf(o[j * 8 + e] * inv);
        *(uint4*)(out + qoff + j * 8) = t.v4;
    }
}

// ---------------------------------------------------------------------------
// out = LayerNorm(a + res) * g + b    (one block per row of D=1024)
// a: bf16; res: f32 or bf16; out: f32 or bf16 (templated)
// ---------------------------------------------------------------------------
__device__ __forceinline__ float ldv(const float* p)  { return *p; }
__device__ __forceinline__ float ldv(const ushort* p) { return bf2f(*p); }
__device__ __forceinline__ void  stv(float* p, float v)  { *p = v; }
__device__ __forceinline__ void  stv(ushort* p, float v) { *p = f2bf(v); }

template <typename RT, typename OT>
__global__ __launch_bounds__(256) void add_ln(
    const ushort* __restrict__ a, const RT* __restrict__ res,
    const float* __restrict__ g, const float* __restrict__ bb,
    OT* __restrict__ out)
{
    const int row = blockIdx.x;
    const int tid = threadIdx.x;
    const size_t base = (size_t)row * DD + tid * 4;

    float x[4];
    float s1 = 0.f, s2 = 0.f;
#pragma unroll
    for (int e = 0; e < 4; ++e) {
        x[e] = bf2f(a[base + e]) + ldv(res + base + e);
        s1 += x[e];
        s2 += x[e] * x[e];
    }
#pragma unroll
    for (int off = 32; off > 0; off >>= 1) {
        s1 += __shfl_down(s1, off, 64);
        s2 += __shfl_down(s2, off, 64);
    }
    __shared__ float r1[4], r2[4];
    const int wave = tid >> 6, lane = tid & 63;
    if (lane == 0) { r1[wave] = s1; r2[wave] = s2; }
    __syncthreads();
    float t1 = r1[0] + r1[1] + r1[2] + r1[3];
    float t2 = r2[0] + r2[1] + r2[2] + r2[3];
    float mu  = t1 * (1.f / DD);
    float var = t2 * (1.f / DD) - mu * mu;
    float rs  = rsqrtf(var + 1e-5f);

#pragma unroll
    for (int e = 0; e < 4; ++e) {
        int col = tid * 4 + e;
        float y = (x[e] - mu) * rs * g[col] + bb[col];
        stv(out + base + e, y);
    }
}

// ---------------------------------------------------------------------------
extern "C" void kernel_launch(void* const* d_in, const int* in_sizes, int n_in,
                              void* d_out, int out_size, void* d_ws, size_t ws_size,
                              hipStream_t stream)
{
    (void)in_sizes; (void)n_in; (void)out_size; (void)ws_size;

    const float* x  = (const float*)d_in[0];
    const float* Wq = (const float*)d_in[1];
    const float* bq = (const float*)d_in[2];
    const float* Wk = (const float*)d_in[3];
    const float* bk = (const float*)d_in[4];
    const float* Wv = (const float*)d_in[5];
    const float* bv = (const float*)d_in[6];
    const float* Wo = (const float*)d_in[7];
    const float* bo = (const float*)d_in[8];
    const float* g1 = (const float*)d_in[9];
    const float* b1 = (const float*)d_in[10];
    const float* W1 = (const float*)d_in[11];
    const float* c1 = (const float*)d_in[12];
    const float* W2 = (const float*)d_in[13];
    const float* c2 = (const float*)d_in[14];
    const float* g2 = (const float*)d_in[15];
    const float* b2 = (const float*)d_in[16];
    float* outp = (float*)d_out;

    char* ws = (char*)d_ws;
    const size_t MB = 1024 * 1024;
    // bf16 workspace layout (120 MiB peak, with reuse):
    ushort* Wqb = (ushort*)(ws);              // [  0,  2) MiB  1M elems
    ushort* Wkb = (ushort*)(ws + 2  * MB);    // [  2,  4)
    ushort* Wvb = (ushort*)(ws + 4  * MB);    // [  4,  6)
    ushort* Wob = (ushort*)(ws + 6  * MB);    // [  6,  8)
    ushort* W1b = (ushort*)(ws + 8  * MB);    // [  8, 16)  4M elems
    ushort* W2b = (ushort*)(ws + 16 * MB);    // [ 16, 24)
    ushort* qb  = (ushort*)(ws + 24 * MB);    // [ 24, 40)  8M elems
    ushort* kb  = (ushort*)(ws + 40 * MB);    // [ 40, 56)
    ushort* vb  = (ushort*)(ws + 56 * MB);    // [ 56, 72)
    ushort* att = (ushort*)(ws + 72 * MB);    // [ 72, 88)
    // reuse after attention:
    ushort* aproj = qb;                       // qb dead after attn
    ushort* hbuf  = kb;                       // kb dead after attn
    ushort* m1  = (ushort*)(ws + 56 * MB);    // [ 56,120) 32M elems (vb+att dead)
    ushort* fbuf  = qb;                       // aproj dead after add_ln1

    dim3 blk(256, 1, 1);
    dim3 gD(DD / 128, MROWS / 128, 1);        // 8 x 64
    dim3 gF(FF / 128, MROWS / 128, 1);        // 32 x 64
    dim3 ga(NBLK, HH, BB);                    // 16 x 16 x 2
    dim3 gl(MROWS, 1, 1);

    // weight conversions (f32 -> bf16 mirrors)
    hipLaunchKernelGGL(cvt_f32_bf16, dim3(1024), blk, 0, stream, Wq, Wqb);
    hipLaunchKernelGGL(cvt_f32_bf16, dim3(1024), blk, 0, stream, Wk, Wkb);
    hipLaunchKernelGGL(cvt_f32_bf16, dim3(1024), blk, 0, stream, Wv, Wvb);
    hipLaunchKernelGGL(cvt_f32_bf16, dim3(1024), blk, 0, stream, Wo, Wob);
    hipLaunchKernelGGL(cvt_f32_bf16, dim3(4096), blk, 0, stream, W1, W1b);
    hipLaunchKernelGGL(cvt_f32_bf16, dim3(4096), blk, 0, stream, W2, W2b);

    // QKV projections (A = x, f32 source converted during staging)
    hipLaunchKernelGGL(gemm_bias<float>, gD, blk, 0, stream, x, Wqb, bq, qb, MROWS, DD, DD, 0);
    hipLaunchKernelGGL(gemm_bias<float>, gD, blk, 0, stream, x, Wkb, bk, kb, MROWS, DD, DD, 0);
    hipLaunchKernelGGL(gemm_bias<float>, gD, blk, 0, stream, x, Wvb, bv, vb, MROWS, DD, DD, 0);

    hipLaunchKernelGGL(attn_kernel, ga, blk, 0, stream, qb, kb, vb, att);

    hipLaunchKernelGGL(gemm_bias<ushort>, gD, blk, 0, stream, att, Wob, bo, aproj, MROWS, DD, DD, 0);
    hipLaunchKernelGGL((add_ln<float, ushort>), gl, blk, 0, stream, aproj, x, g1, b1, hbuf);

    hipLaunchKernelGGL(gemm_bias<ushort>, gF, blk, 0, stream, hbuf, W1b, c1, m1, MROWS, FF, DD, 1);
    hipLaunchKernelGGL(gemm_bias<ushort>, gD, blk, 0, stream, m1, W2b, c2, fbuf, MROWS, DD, FF, 0);
    hipLaunchKernelGGL((add_ln<ushort, float>), gl, blk, 0, stream, fbuf, hbuf, g2, b2, outp);
}

// Round 3
// 662.763 us; speedup vs baseline: 2.1812x; 2.1812x over previous
//
#include <hip/hip_runtime.h>
#include <hip/hip_bf16.h>

#define BB 2
#define SS 4096
#define DD 1024
#define HH 16
#define WW 256
#define FF 4096
#define HDIM 64
#define NBLK (SS / WW)       /* 16 */
#define MROWS (BB * SS)      /* 8192 */

typedef short bfrag8 __attribute__((ext_vector_type(8)));
typedef float floatx4 __attribute__((ext_vector_type(4)));

__device__ __forceinline__ float bf2f(ushort u) {
    union { uint i; float f; } c; c.i = ((uint)u) << 16; return c.f;
}
__device__ __forceinline__ ushort f2bf(float f) {
    union { float f; uint i; } c; c.f = f;
    uint r = (c.i + 0x7FFFu + ((c.i >> 16) & 1u)) >> 16;
    return (ushort)r;
}
__device__ __forceinline__ float gelu_tanh(float x) {
    float x3 = x * x * x;
    return 0.5f * x * (1.f + tanhf(0.7978845608028654f * (x + 0.044715f * x3)));
}

// async global->LDS, 16B per lane. LDS dest must be contiguous in lane order.
__device__ __forceinline__ void gload_lds16(const ushort* g, ushort* l) {
    __builtin_amdgcn_global_load_lds(
        (const __attribute__((address_space(1))) void*)g,
        (__attribute__((address_space(3))) void*)l, 16, 0, 0);
}

// ---------------------------------------------------------------------------
// f32 -> bf16 bulk convert (grid * 1024 elements)
// ---------------------------------------------------------------------------
__global__ __launch_bounds__(256) void cvt_f32_bf16(
    const float* __restrict__ in, ushort* __restrict__ out)
{
    size_t i = ((size_t)blockIdx.x * 256 + threadIdx.x) * 4;
    float4 v = *(const float4*)(in + i);
    union { ushort u[4]; uint2 d; } t;
    t.u[0] = f2bf(v.x); t.u[1] = f2bf(v.y);
    t.u[2] = f2bf(v.z); t.u[3] = f2bf(v.w);
    *(uint2*)(out + i) = t.d;
}

// ---------------------------------------------------------------------------
// f32 [K][N] -> bf16 [N][K] transpose-convert, 32x32 LDS tiles.
// grid = (N/32, K/32)
// ---------------------------------------------------------------------------
__global__ __launch_bounds__(256) void cvt_transpose(
    const float* __restrict__ in, ushort* __restrict__ out, int K, int N)
{
    __shared__ ushort sT[32][33];
    const int n0 = blockIdx.x * 32, k0 = blockIdx.y * 32;
    const int r  = threadIdx.x >> 3;        // 0..31
    const int c4 = (threadIdx.x & 7) * 4;   // 0..28

    float4 v = *(const float4*)(in + (size_t)(k0 + r) * N + n0 + c4);
    sT[c4 + 0][r] = f2bf(v.x);
    sT[c4 + 1][r] = f2bf(v.y);
    sT[c4 + 2][r] = f2bf(v.z);
    sT[c4 + 3][r] = f2bf(v.w);
    __syncthreads();
    union { ushort u[4]; uint2 d; } t;
#pragma unroll
    for (int e = 0; e < 4; ++e) t.u[e] = sT[r][c4 + e];
    *(uint2*)(out + (size_t)(n0 + r) * K + k0 + c4) = t.d;
}

// ---------------------------------------------------------------------------
// GEMM: C[M,N] = A[M,K] @ B[K,N] + bias[N], with Bt = B^T in [N][K] bf16.
// m97 structure: 128x128 tile, BK=32, global_load_lds width-16 staging,
// unpadded LDS, 4 waves x (4x4) MFMA 16x16x32 bf16. act: 1 = gelu.
// ---------------------------------------------------------------------------
__global__ __launch_bounds__(256) void gemm_bt(
    const ushort* __restrict__ A, const ushort* __restrict__ Bt,
    const float* __restrict__ bias, ushort* __restrict__ C,
    int M, int N, int K, int act)
{
    __shared__ ushort sA[128 * 32];
    __shared__ ushort sB[128 * 32];

    const int tid  = threadIdx.x;
    const int m0   = blockIdx.y * 128;
    const int n0   = blockIdx.x * 128;
    const int wave = tid >> 6;
    const int lane = tid & 63;
    const int wm   = (wave >> 1) * 64;
    const int wn   = (wave & 1) * 64;
    const int lrow = lane & 15;
    const int quad = lane >> 4;

    floatx4 acc[4][4];
#pragma unroll
    for (int i = 0; i < 4; ++i)
#pragma unroll
        for (int j = 0; j < 4; ++j)
            acc[i][j] = (floatx4){0.f, 0.f, 0.f, 0.f};

    for (int k0 = 0; k0 < K; k0 += 32) {
#pragma unroll
        for (int it = 0; it < 2; ++it) {
            int c = it * 256 + tid;               // 512 chunks of 16B per tile
            gload_lds16(A  + (size_t)(m0 + (c >> 2)) * K + k0 + (c & 3) * 8, &sA[c * 8]);
            gload_lds16(Bt + (size_t)(n0 + (c >> 2)) * K + k0 + (c & 3) * 8, &sB[c * 8]);
        }
        __syncthreads();   // drains vmcnt (global_load_lds) per barrier semantics

        bfrag8 af[4], bfv[4];
#pragma unroll
        for (int mt = 0; mt < 4; ++mt)
            af[mt] = *(const bfrag8*)&sA[(wm + mt * 16 + lrow) * 32 + quad * 8];
#pragma unroll
        for (int nt = 0; nt < 4; ++nt)
            bfv[nt] = *(const bfrag8*)&sB[(wn + nt * 16 + lrow) * 32 + quad * 8];
#pragma unroll
        for (int mt = 0; mt < 4; ++mt)
#pragma unroll
            for (int nt = 0; nt < 4; ++nt)
                acc[mt][nt] = __builtin_amdgcn_mfma_f32_16x16x32_bf16(
                    af[mt], bfv[nt], acc[mt][nt], 0, 0, 0);
        __syncthreads();
    }

    // epilogue: C/D layout col = lane&15, row = quad*4 + reg
#pragma unroll
    for (int nt = 0; nt < 4; ++nt) {
        int col = n0 + wn + nt * 16 + lrow;
        float bb = bias[col];
#pragma unroll
        for (int mt = 0; mt < 4; ++mt) {
#pragma unroll
            for (int r = 0; r < 4; ++r) {
                int row = m0 + wm + mt * 16 + (quad << 2) + r;
                float v = acc[mt][nt][r] + bb;
                if (act) v = gelu_tanh(v);
                C[(size_t)row * N + col] = f2bf(v);
            }
        }
    }
}

// ---------------------------------------------------------------------------
// MFMA flash sliding-window attention.
// Block = (n, h, b), 4 waves; wave w owns 64 query rows. Per 64-key subtile:
//   S^T = K·Q^T (MFMA, C-layout: key=quad*4+r, qrow=lane&15) -> online softmax
//   (stats lane-aligned, 2 cross-quad shuffles) -> P to per-wave LDS
//   (ds_write_b64) -> O^T += V^T·P^T (P^T read back as B-frag via ds_read_b128,
//   V^T staged per chunk). Band mask: masked = -1e30, exp2 underflow == ref.
// ---------------------------------------------------------------------------
__global__ __launch_bounds__(256) void attn_mfma(
    const ushort* __restrict__ q, const ushort* __restrict__ k,
    const ushort* __restrict__ v, ushort* __restrict__ out)
{
    __shared__ ushort sVT[64 * 264];     // V^T [d][key], stride 264 (16B-aligned rows)
    __shared__ ushort sP[4][64 * 72];    // per-wave P [qrow][key], stride 72

    const int n = blockIdx.x, h = blockIdx.y, b = blockIdx.z;
    const int tid  = threadIdx.x;
    const int w    = tid >> 6;
    const int lane = tid & 63;
    const int c16  = lane & 15;
    const int quad = lane >> 4;
    const float CC = 0.18033688011112042f;   // (1/sqrt(64)) * log2(e)

    // Q fragments (B-operand layout): qrow = w*64 + nt*16 + c16
    bfrag8 qf[4][2];
    {
        const size_t qbase = ((size_t)b * SS + n * WW + w * 64) * DD + h * HDIM;
#pragma unroll
        for (int nt = 0; nt < 4; ++nt)
#pragma unroll
            for (int ks = 0; ks < 2; ++ks)
                qf[nt][ks] = *(const bfrag8*)(q + qbase + (size_t)(nt * 16 + c16) * DD + ks * 32 + quad * 8);
    }

    floatx4 oacc[4][4];   // O^T acc [dt][nq]: row d=quad*4+r, col qrow=c16
#pragma unroll
    for (int i = 0; i < 4; ++i)
#pragma unroll
        for (int j = 0; j < 4; ++j)
            oacc[i][j] = (floatx4){0.f, 0.f, 0.f, 0.f};
    float mrow[4], lsum[4];
#pragma unroll
    for (int i = 0; i < 4; ++i) { mrow[i] = -1e30f; lsum[i] = 0.f; }

    ushort* sPw = sP[w];

    for (int cb = n - 1; cb <= n + 1; ++cb) {
        if (cb < 0 || cb >= NBLK) continue;        // block-uniform
        const int mode = cb - n;                   // -1 / 0 / +1
        const size_t kvbase = ((size_t)b * SS + cb * WW) * DD + h * HDIM;

        __syncthreads();
        {   // stage V^T: thread reads 8 keys x 8 dims, register transpose,
            // vector LDS writes
            const int d0 = (tid & 7) * 8, kb0 = (tid >> 3) * 8;
            ushort tmp[8][8];
#pragma unroll
            for (int kk = 0; kk < 8; ++kk) {
                union { uint4 v4; ushort u[8]; } t;
                t.v4 = *(const uint4*)(v + kvbase + (size_t)(kb0 + kk) * DD + d0);
#pragma unroll
                for (int e = 0; e < 8; ++e) tmp[e][kk] = t.u[e];
            }
#pragma unroll
            for (int e = 0; e < 8; ++e)
                *(uint4*)&sVT[(d0 + e) * 264 + kb0] = *(const uint4*)tmp[e];
        }
        __syncthreads();

        for (int st = 0; st < 4; ++st) {
            if (mode < 0 && st < w) continue;      // fully-masked subtiles
            if (mode > 0 && st > w) continue;      // (wave-uniform skip)
            const bool part = (mode != 0) && (st == w);

            // S^T = K · Q^T over 64 keys
            floatx4 sacc[4][4];
#pragma unroll
            for (int i = 0; i < 4; ++i)
#pragma unroll
                for (int j = 0; j < 4; ++j)
                    sacc[i][j] = (floatx4){0.f, 0.f, 0.f, 0.f};
#pragma unroll
            for (int ks = 0; ks < 2; ++ks) {
                bfrag8 kf[4];
#pragma unroll
                for (int mt = 0; mt < 4; ++mt)
                    kf[mt] = *(const bfrag8*)(k + kvbase +
                        (size_t)(st * 64 + mt * 16 + c16) * DD + ks * 32 + quad * 8);
#pragma unroll
                for (int mt = 0; mt < 4; ++mt)
#pragma unroll
                    for (int nt = 0; nt < 4; ++nt)
                        sacc[mt][nt] = __builtin_amdgcn_mfma_f32_16x16x32_bf16(
                            kf[mt], qf[nt][ks], sacc[mt][nt], 0, 0, 0);
            }

            if (part) {
#pragma unroll
                for (int mt = 0; mt < 4; ++mt)
#pragma unroll
                    for (int nt = 0; nt < 4; ++nt)
#pragma unroll
                        for (int r = 0; r < 4; ++r) {
                            int kl = mt * 16 + quad * 4 + r;
                            int ql = nt * 16 + c16;
                            bool ok = (mode < 0) ? (kl >= ql) : (kl <= ql);
                            if (!ok) sacc[mt][nt][r] = -1e30f;
                        }
            }

            // row max (4 qrows/lane), cross-quad reduce
            float pm[4];
#pragma unroll
            for (int nt = 0; nt < 4; ++nt) {
                float a0 = fmaxf(fmaxf(sacc[0][nt][0], sacc[0][nt][1]),
                                 fmaxf(sacc[0][nt][2], sacc[0][nt][3]));
                float a1 = fmaxf(fmaxf(sacc[1][nt][0], sacc[1][nt][1]),
                                 fmaxf(sacc[1][nt][2], sacc[1][nt][3]));
                float a2 = fmaxf(fmaxf(sacc[2][nt][0], sacc[2][nt][1]),
                                 fmaxf(sacc[2][nt][2], sacc[2][nt][3]));
                float a3 = fmaxf(fmaxf(sacc[3][nt][0], sacc[3][nt][1]),
                                 fmaxf(sacc[3][nt][2], sacc[3][nt][3]));
                pm[nt] = fmaxf(fmaxf(a0, a1), fmaxf(a2, a3));
                pm[nt] = fmaxf(pm[nt], __shfl_xor(pm[nt], 16, 64));
                pm[nt] = fmaxf(pm[nt], __shfl_xor(pm[nt], 32, 64));
            }
            float al[4];
#pragma unroll
            for (int nt = 0; nt < 4; ++nt) {
                float mn = fmaxf(mrow[nt], pm[nt]);
                al[nt] = exp2f((mrow[nt] - mn) * CC);
                mrow[nt] = mn;
            }
            float ps[4] = {0.f, 0.f, 0.f, 0.f};
#pragma unroll
            for (int mt = 0; mt < 4; ++mt)
#pragma unroll
                for (int nt = 0; nt < 4; ++nt)
#pragma unroll
                    for (int r = 0; r < 4; ++r) {
                        float p = exp2f((sacc[mt][nt][r] - mrow[nt]) * CC);
                        sacc[mt][nt][r] = p;
                        ps[nt] += p;
                    }
#pragma unroll
            for (int nt = 0; nt < 4; ++nt) {
                ps[nt] += __shfl_xor(ps[nt], 16, 64);
                ps[nt] += __shfl_xor(ps[nt], 32, 64);
                lsum[nt] = lsum[nt] * al[nt] + ps[nt];
            }

            // P (bf16) -> per-wave LDS, rows=qrow, cols=key(0..63)
#pragma unroll
            for (int mt = 0; mt < 4; ++mt)
#pragma unroll
                for (int nt = 0; nt < 4; ++nt) {
                    union { ushort u[4]; uint2 d; } t;
#pragma unroll
                    for (int r = 0; r < 4; ++r) t.u[r] = f2bf(sacc[mt][nt][r]);
                    *(uint2*)&sPw[(nt * 16 + c16) * 72 + mt * 16 + quad * 4] = t.d;
                }

            // rescale O^T
#pragma unroll
            for (int dt = 0; dt < 4; ++dt)
#pragma unroll
                for (int nq = 0; nq < 4; ++nq)
#pragma unroll
                    for (int r = 0; r < 4; ++r)
                        oacc[dt][nq][r] *= al[nq];

            // O^T += V^T · P^T
#pragma unroll
            for (int ks = 0; ks < 2; ++ks) {
                bfrag8 vf[4], pf[4];
#pragma unroll
                for (int dt = 0; dt < 4; ++dt)
                    vf[dt] = *(const bfrag8*)&sVT[(c16 + dt * 16) * 264 + st * 64 + ks * 32 + quad * 8];
#pragma unroll
                for (int nq = 0; nq < 4; ++nq)
                    pf[nq] = *(const bfrag8*)&sPw[(nq * 16 + c16) * 72 + ks * 32 + quad * 8];
#pragma unroll
                for (int dt = 0; dt < 4; ++dt)
#pragma unroll
                    for (int nq = 0; nq < 4; ++nq)
                        oacc[dt][nq] = __builtin_amdgcn_mfma_f32_16x16x32_bf16(
                            vf[dt], pf[nq], oacc[dt][nq], 0, 0, 0);
            }
        }
    }

    // normalize + store (O^T C-layout: d = dt*16+quad*4+r, qrow = nq*16+c16)
#pragma unroll
    for (int nq = 0; nq < 4; ++nq) {
        float inv = 1.f / lsum[nq];
        size_t rbase = ((size_t)b * SS + n * WW + w * 64 + nq * 16 + c16) * DD + h * HDIM;
#pragma unroll
        for (int dt = 0; dt < 4; ++dt) {
            union { ushort u[4]; uint2 d; } t;
#pragma unroll
            for (int r = 0; r < 4; ++r) t.u[r] = f2bf(oacc[dt][nq][r] * inv);
            *(uint2*)(out + rbase + dt * 16 + quad * 4) = t.d;
        }
    }
}

// ---------------------------------------------------------------------------
// out = LayerNorm(a + res) * g + b    (one block per row of D=1024)
// ---------------------------------------------------------------------------
__device__ __forceinline__ float ldv(const float* p)  { return *p; }
__device__ __forceinline__ float ldv(const ushort* p) { return bf2f(*p); }
__device__ __forceinline__ void  stv(float* p, float v)  { *p = v; }
__device__ __forceinline__ void  stv(ushort* p, float v) { *p = f2bf(v); }

template <typename RT, typename OT>
__global__ __launch_bounds__(256) void add_ln(
    const ushort* __restrict__ a, const RT* __restrict__ res,
    const float* __restrict__ g, const float* __restrict__ bb,
    OT* __restrict__ out)
{
    const int row = blockIdx.x;
    const int tid = threadIdx.x;
    const size_t base = (size_t)row * DD + tid * 4;

    float x[4];
    float s1 = 0.f, s2 = 0.f;
#pragma unroll
    for (int e = 0; e < 4; ++e) {
        x[e] = bf2f(a[base + e]) + ldv(res + base + e);
        s1 += x[e];
        s2 += x[e] * x[e];
    }
#pragma unroll
    for (int off = 32; off > 0; off >>= 1) {
        s1 += __shfl_down(s1, off, 64);
        s2 += __shfl_down(s2, off, 64);
    }
    __shared__ float r1[4], r2[4];
    const int wave = tid >> 6, lane = tid & 63;
    if (lane == 0) { r1[wave] = s1; r2[wave] = s2; }
    __syncthreads();
    float t1 = r1[0] + r1[1] + r1[2] + r1[3];
    float t2 = r2[0] + r2[1] + r2[2] + r2[3];
    float mu  = t1 * (1.f / DD);
    float var = t2 * (1.f / DD) - mu * mu;
    float rs  = rsqrtf(var + 1e-5f);

#pragma unroll
    for (int e = 0; e < 4; ++e) {
        int col = tid * 4 + e;
        float y = (x[e] - mu) * rs * g[col] + bb[col];
        stv(out + base + e, y);
    }
}

// ---------------------------------------------------------------------------
extern "C" void kernel_launch(void* const* d_in, const int* in_sizes, int n_in,
                              void* d_out, int out_size, void* d_ws, size_t ws_size,
                              hipStream_t stream)
{
    (void)in_sizes; (void)n_in; (void)out_size; (void)ws_size;

    const float* x  = (const float*)d_in[0];
    const float* Wq = (const float*)d_in[1];
    const float* bq = (const float*)d_in[2];
    const float* Wk = (const float*)d_in[3];
    const float* bk = (const float*)d_in[4];
    const float* Wv = (const float*)d_in[5];
    const float* bv = (const float*)d_in[6];
    const float* Wo = (const float*)d_in[7];
    const float* bo = (const float*)d_in[8];
    const float* g1 = (const float*)d_in[9];
    const float* b1 = (const float*)d_in[10];
    const float* W1 = (const float*)d_in[11];
    const float* c1 = (const float*)d_in[12];
    const float* W2 = (const float*)d_in[13];
    const float* c2 = (const float*)d_in[14];
    const float* g2 = (const float*)d_in[15];
    const float* b2 = (const float*)d_in[16];
    float* outp = (float*)d_out;

    char* ws = (char*)d_ws;
    const size_t MB = 1024 * 1024;
    // bf16 workspace (peak 120 MiB with reuse):
    ushort* Wqt = (ushort*)(ws);              // [  0,  2) MiB, [N][K]
    ushort* Wkt = (ushort*)(ws + 2  * MB);
    ushort* Wvt = (ushort*)(ws + 4  * MB);
    ushort* Wot = (ushort*)(ws + 6  * MB);
    ushort* W1t = (ushort*)(ws + 8  * MB);    // [  8, 16)  [4096][1024]
    ushort* W2t = (ushort*)(ws + 16 * MB);    // [ 16, 24)  [1024][4096]
    ushort* xb  = (ushort*)(ws + 24 * MB);    // [ 24, 40)
    ushort* qb  = (ushort*)(ws + 40 * MB);    // [ 40, 56)
    ushort* kb  = (ushort*)(ws + 56 * MB);    // [ 56, 72)
    ushort* vb  = (ushort*)(ws + 72 * MB);    // [ 72, 88)
    ushort* att = (ushort*)(ws + 88 * MB);    // [ 88,104)
    ushort* aproj = qb;                       // qb dead after attn
    ushort* hbuf  = att;                      // att dead after Wo-gemm
    ushort* m1  = (ushort*)(ws + 24 * MB);    // [ 24, 88): xb/qb/kb/vb dead
    ushort* fbuf = (ushort*)(ws + 104 * MB);  // [104,120)

    dim3 blk(256, 1, 1);
    dim3 gD(DD / 128, MROWS / 128, 1);        // 8 x 64
    dim3 gF(FF / 128, MROWS / 128, 1);        // 32 x 64
    dim3 ga(NBLK, HH, BB);                    // 16 x 16 x 2
    dim3 gl(MROWS, 1, 1);

    // weight transpose-converts ([K][N] f32 -> [N][K] bf16) + x convert
    hipLaunchKernelGGL(cvt_transpose, dim3(32, 32),  blk, 0, stream, Wq, Wqt, DD, DD);
    hipLaunchKernelGGL(cvt_transpose, dim3(32, 32),  blk, 0, stream, Wk, Wkt, DD, DD);
    hipLaunchKernelGGL(cvt_transpose, dim3(32, 32),  blk, 0, stream, Wv, Wvt, DD, DD);
    hipLaunchKernelGGL(cvt_transpose, dim3(32, 32),  blk, 0, stream, Wo, Wot, DD, DD);
    hipLaunchKernelGGL(cvt_transpose, dim3(128, 32), blk, 0, stream, W1, W1t, DD, FF);
    hipLaunchKernelGGL(cvt_transpose, dim3(32, 128), blk, 0, stream, W2, W2t, FF, DD);
    hipLaunchKernelGGL(cvt_f32_bf16, dim3(8192), blk, 0, stream, x, xb);

    // QKV projections
    hipLaunchKernelGGL(gemm_bt, gD, blk, 0, stream, xb, Wqt, bq, qb, MROWS, DD, DD, 0);
    hipLaunchKernelGGL(gemm_bt, gD, blk, 0, stream, xb, Wkt, bk, kb, MROWS, DD, DD, 0);
    hipLaunchKernelGGL(gemm_bt, gD, blk, 0, stream, xb, Wvt, bv, vb, MROWS, DD, DD, 0);

    hipLaunchKernelGGL(attn_mfma, ga, blk, 0, stream, qb, kb, vb, att);

    hipLaunchKernelGGL(gemm_bt, gD, blk, 0, stream, att, Wot, bo, aproj, MROWS, DD, DD, 0);
    hipLaunchKernelGGL((add_ln<float, ushort>), gl, blk, 0, stream, aproj, x, g1, b1, hbuf);

    hipLaunchKernelGGL(gemm_bt, gF, blk, 0, stream, hbuf, W1t, c1, m1, MROWS, FF, DD, 1);
    hipLaunchKernelGGL(gemm_bt, gD, blk, 0, stream, m1, W2t, c2, fbuf, MROWS, DD, FF, 0);
    hipLaunchKernelGGL((add_ln<ushort, float>), gl, blk, 0, stream, fbuf, hbuf, g2, b2, outp);
}

// Round 4
// 584.812 us; speedup vs baseline: 2.4720x; 1.1333x over previous
//
#include <hip/hip_runtime.h>
#include <hip/hip_bf16.h>

#define BB 2
#define SS 4096
#define DD 1024
#define HH 16
#define WW 256
#define FF 4096
#define HDIM 64
#define NBLK (SS / WW)       /* 16 */
#define MROWS (BB * SS)      /* 8192 */

typedef short bfrag8 __attribute__((ext_vector_type(8)));
typedef float floatx4 __attribute__((ext_vector_type(4)));

__device__ __forceinline__ float bf2f(ushort u) {
    union { uint i; float f; } c; c.i = ((uint)u) << 16; return c.f;
}
__device__ __forceinline__ ushort f2bf(float f) {
    union { float f; uint i; } c; c.f = f;
    uint r = (c.i + 0x7FFFu + ((c.i >> 16) & 1u)) >> 16;
    return (ushort)r;
}
__device__ __forceinline__ float gelu_tanh(float x) {
    float x3 = x * x * x;
    return 0.5f * x * (1.f + tanhf(0.7978845608028654f * (x + 0.044715f * x3)));
}

// async global->LDS, 16B per lane. LDS dest must be contiguous in lane order.
__device__ __forceinline__ void gload_lds16(const ushort* g, ushort* l) {
    __builtin_amdgcn_global_load_lds(
        (const __attribute__((address_space(1))) void*)g,
        (__attribute__((address_space(3))) void*)l, 16, 0, 0);
}

// ---------------------------------------------------------------------------
// f32 -> bf16 bulk convert (grid * 1024 elements)
// ---------------------------------------------------------------------------
__global__ __launch_bounds__(256) void cvt_f32_bf16(
    const float* __restrict__ in, ushort* __restrict__ out)
{
    size_t i = ((size_t)blockIdx.x * 256 + threadIdx.x) * 4;
    float4 v = *(const float4*)(in + i);
    union { ushort u[4]; uint2 d; } t;
    t.u[0] = f2bf(v.x); t.u[1] = f2bf(v.y);
    t.u[2] = f2bf(v.z); t.u[3] = f2bf(v.w);
    *(uint2*)(out + i) = t.d;
}

// ---------------------------------------------------------------------------
// f32 [K][N] -> bf16 [N][K] transpose-convert, 32x32 LDS tiles.
// grid = (N/32, K/32)
// ---------------------------------------------------------------------------
__global__ __launch_bounds__(256) void cvt_transpose(
    const float* __restrict__ in, ushort* __restrict__ out, int K, int N)
{
    __shared__ ushort sT[32][33];
    const int n0 = blockIdx.x * 32, k0 = blockIdx.y * 32;
    const int r  = threadIdx.x >> 3;        // 0..31
    const int c4 = (threadIdx.x & 7) * 4;   // 0..28

    float4 v = *(const float4*)(in + (size_t)(k0 + r) * N + n0 + c4);
    sT[c4 + 0][r] = f2bf(v.x);
    sT[c4 + 1][r] = f2bf(v.y);
    sT[c4 + 2][r] = f2bf(v.z);
    sT[c4 + 3][r] = f2bf(v.w);
    __syncthreads();
    union { ushort u[4]; uint2 d; } t;
#pragma unroll
    for (int e = 0; e < 4; ++e) t.u[e] = sT[r][c4 + e];
    *(uint2*)(out + (size_t)(n0 + r) * K + k0 + c4) = t.d;
}

// ---------------------------------------------------------------------------
// GEMM: C[M,N] = A[M,K] @ B[K,N] + bias[N], Bt = B^T [N][K] bf16.
// m97 structure: 128x128 tile, BK=32, global_load_lds width-16 staging.
// ---------------------------------------------------------------------------
__global__ __launch_bounds__(256) void gemm_bt(
    const ushort* __restrict__ A, const ushort* __restrict__ Bt,
    const float* __restrict__ bias, ushort* __restrict__ C,
    int M, int N, int K, int act)
{
    __shared__ ushort sA[128 * 32];
    __shared__ ushort sB[128 * 32];

    const int tid  = threadIdx.x;
    const int m0   = blockIdx.y * 128;
    const int n0   = blockIdx.x * 128;
    const int wave = tid >> 6;
    const int lane = tid & 63;
    const int wm   = (wave >> 1) * 64;
    const int wn   = (wave & 1) * 64;
    const int lrow = lane & 15;
    const int quad = lane >> 4;

    floatx4 acc[4][4];
#pragma unroll
    for (int i = 0; i < 4; ++i)
#pragma unroll
        for (int j = 0; j < 4; ++j)
            acc[i][j] = (floatx4){0.f, 0.f, 0.f, 0.f};

    for (int k0 = 0; k0 < K; k0 += 32) {
#pragma unroll
        for (int it = 0; it < 2; ++it) {
            int c = it * 256 + tid;
            gload_lds16(A  + (size_t)(m0 + (c >> 2)) * K + k0 + (c & 3) * 8, &sA[c * 8]);
            gload_lds16(Bt + (size_t)(n0 + (c >> 2)) * K + k0 + (c & 3) * 8, &sB[c * 8]);
        }
        __syncthreads();

        bfrag8 af[4], bfv[4];
#pragma unroll
        for (int mt = 0; mt < 4; ++mt)
            af[mt] = *(const bfrag8*)&sA[(wm + mt * 16 + lrow) * 32 + quad * 8];
#pragma unroll
        for (int nt = 0; nt < 4; ++nt)
            bfv[nt] = *(const bfrag8*)&sB[(wn + nt * 16 + lrow) * 32 + quad * 8];
#pragma unroll
        for (int mt = 0; mt < 4; ++mt)
#pragma unroll
            for (int nt = 0; nt < 4; ++nt)
                acc[mt][nt] = __builtin_amdgcn_mfma_f32_16x16x32_bf16(
                    af[mt], bfv[nt], acc[mt][nt], 0, 0, 0);
        __syncthreads();
    }

#pragma unroll
    for (int nt = 0; nt < 4; ++nt) {
        int col = n0 + wn + nt * 16 + lrow;
        float bb = bias[col];
#pragma unroll
        for (int mt = 0; mt < 4; ++mt) {
#pragma unroll
            for (int r = 0; r < 4; ++r) {
                int row = m0 + wm + mt * 16 + (quad << 2) + r;
                float v = acc[mt][nt][r] + bb;
                if (act) v = gelu_tanh(v);
                C[(size_t)row * N + col] = f2bf(v);
            }
        }
    }
}

// ---------------------------------------------------------------------------
// Fused QKV GEMM: A[8192][1024] @ [Wq|Wk|Wv] (Bt = [3072][1024]).
// cols [0,1024) -> qb [token][1024]; [1024,2048) -> kb; [2048,3072) -> vT
// transposed as [b][h][dh][s] for contiguous V^T fragment loads in attention.
// ---------------------------------------------------------------------------
__global__ __launch_bounds__(256) void gemm_qkv(
    const ushort* __restrict__ A, const ushort* __restrict__ Bt,
    const float* __restrict__ bq, const float* __restrict__ bk,
    const float* __restrict__ bv,
    ushort* __restrict__ qb, ushort* __restrict__ kb, ushort* __restrict__ vT)
{
    __shared__ ushort sA[128 * 32];
    __shared__ ushort sB[128 * 32];
    const int K = DD, N = 3 * DD;

    const int tid  = threadIdx.x;
    const int m0   = blockIdx.y * 128;
    const int n0   = blockIdx.x * 128;
    const int wave = tid >> 6;
    const int lane = tid & 63;
    const int wm   = (wave >> 1) * 64;
    const int wn   = (wave & 1) * 64;
    const int lrow = lane & 15;
    const int quad = lane >> 4;

    floatx4 acc[4][4];
#pragma unroll
    for (int i = 0; i < 4; ++i)
#pragma unroll
        for (int j = 0; j < 4; ++j)
            acc[i][j] = (floatx4){0.f, 0.f, 0.f, 0.f};

    for (int k0 = 0; k0 < K; k0 += 32) {
#pragma unroll
        for (int it = 0; it < 2; ++it) {
            int c = it * 256 + tid;
            gload_lds16(A  + (size_t)(m0 + (c >> 2)) * K + k0 + (c & 3) * 8, &sA[c * 8]);
            gload_lds16(Bt + (size_t)(n0 + (c >> 2)) * K + k0 + (c & 3) * 8, &sB[c * 8]);
        }
        __syncthreads();

        bfrag8 af[4], bfv[4];
#pragma unroll
        for (int mt = 0; mt < 4; ++mt)
            af[mt] = *(const bfrag8*)&sA[(wm + mt * 16 + lrow) * 32 + quad * 8];
#pragma unroll
        for (int nt = 0; nt < 4; ++nt)
            bfv[nt] = *(const bfrag8*)&sB[(wn + nt * 16 + lrow) * 32 + quad * 8];
#pragma unroll
        for (int mt = 0; mt < 4; ++mt)
#pragma unroll
            for (int nt = 0; nt < 4; ++nt)
                acc[mt][nt] = __builtin_amdgcn_mfma_f32_16x16x32_bf16(
                    af[mt], bfv[nt], acc[mt][nt], 0, 0, 0);
        __syncthreads();
    }

    const int colbase = n0 + wn;
    const int sel = colbase >> 10;           // 0=q 1=k 2=v (uniform per wave)
    if (sel < 2) {
        ushort* C = (sel == 0) ? qb : kb;
        const float* bias = (sel == 0) ? bq : bk;
#pragma unroll
        for (int nt = 0; nt < 4; ++nt) {
            int cc = (colbase + nt * 16 + lrow) & 1023;
            float bb = bias[cc];
#pragma unroll
            for (int mt = 0; mt < 4; ++mt)
#pragma unroll
                for (int r = 0; r < 4; ++r) {
                    int row = m0 + wm + mt * 16 + (quad << 2) + r;
                    C[(size_t)row * DD + cc] = f2bf(acc[mt][nt][r] + bb);
                }
        }
    } else {
        // vT[b][h][dh][s]; lane's 4 acc regs are contiguous in s -> uint2
#pragma unroll
        for (int nt = 0; nt < 4; ++nt) {
            int cc = (colbase + nt * 16 + lrow) & 1023;
            int h = cc >> 6, dh = cc & 63;
            float bb = bv[cc];
#pragma unroll
            for (int mt = 0; mt < 4; ++mt) {
                int row0 = m0 + wm + mt * 16 + (quad << 2);
                int b = row0 >> 12, s = row0 & 4095;
                union { ushort u[4]; uint2 d; } t;
#pragma unroll
                for (int r = 0; r < 4; ++r) t.u[r] = f2bf(acc[mt][nt][r] + bb);
                *(uint2*)(vT + (size_t)(((b * HH + h) * HDIM + dh)) * SS + s) = t.d;
            }
        }
    }
}

// ---------------------------------------------------------------------------
// Barrier-free MFMA flash attention. One wave per block; block = (qt, h, b);
// wave owns q rows [qt*64, qt*64+64). Keys: subtiles st in [qt-4, qt+4]
// (band |q-key| <= 256), |delta|==4 partially masked.
//   S^T = K·Q^T (MFMA) -> online softmax (stats lane-aligned, 2 shuffles)
//   -> P via swizzled LDS (granule^row&3, stride 72: <=2-way banks)
//   -> O^T += V^T·P^T, V^T fragments straight from global vT (contiguous 16B).
// No __syncthreads anywhere; 2048 independent waves.
// ---------------------------------------------------------------------------
__global__ __launch_bounds__(64, 2) void attn_flash(
    const ushort* __restrict__ q, const ushort* __restrict__ k,
    const ushort* __restrict__ vT, ushort* __restrict__ out)
{
    __shared__ ushort sP[64 * 72];

    const int qt = blockIdx.x, h = blockIdx.y, b = blockIdx.z;
    const int lane = threadIdx.x;
    const int c16  = lane & 15;
    const int quad = lane >> 4;
    const float CC = 0.18033688011112042f;   // (1/sqrt(64)) * log2(e)

    // Q fragments (B-operand): qrow = nt*16 + c16
    bfrag8 qf[4][2];
    {
        const size_t qbase = ((size_t)b * SS + qt * 64) * DD + h * HDIM;
#pragma unroll
        for (int nt = 0; nt < 4; ++nt)
#pragma unroll
            for (int ks = 0; ks < 2; ++ks)
                qf[nt][ks] = *(const bfrag8*)(q + qbase +
                    (size_t)(nt * 16 + c16) * DD + ks * 32 + quad * 8);
    }

    floatx4 oacc[4][4];   // O^T: row d=dt*16+quad*4+r, col qrow=nq*16+c16
#pragma unroll
    for (int i = 0; i < 4; ++i)
#pragma unroll
        for (int j = 0; j < 4; ++j)
            oacc[i][j] = (floatx4){0.f, 0.f, 0.f, 0.f};
    float mrow[4], lsum[4];
#pragma unroll
    for (int i = 0; i < 4; ++i) { mrow[i] = -1e30f; lsum[i] = 0.f; }

    const int st0 = (qt - 4 > 0) ? qt - 4 : 0;
    const int st1 = (qt + 4 < 63) ? qt + 4 : 63;
    const size_t kb_b  = (size_t)b * SS * DD + h * HDIM;
    const size_t vT_b  = (size_t)((b * HH + h) * HDIM) * SS;

    for (int st = st0; st <= st1; ++st) {
        const int dlt = st - qt;

        // S^T = K · Q^T over this 64-key subtile
        floatx4 sacc[4][4];
#pragma unroll
        for (int i = 0; i < 4; ++i)
#pragma unroll
            for (int j = 0; j < 4; ++j)
                sacc[i][j] = (floatx4){0.f, 0.f, 0.f, 0.f};
#pragma unroll
        for (int ks = 0; ks < 2; ++ks) {
            bfrag8 kf[4];
#pragma unroll
            for (int mt = 0; mt < 4; ++mt)
                kf[mt] = *(const bfrag8*)(k + kb_b +
                    (size_t)(st * 64 + mt * 16 + c16) * DD + ks * 32 + quad * 8);
#pragma unroll
            for (int mt = 0; mt < 4; ++mt)
#pragma unroll
                for (int nt = 0; nt < 4; ++nt)
                    sacc[mt][nt] = __builtin_amdgcn_mfma_f32_16x16x32_bf16(
                        kf[mt], qf[nt][ks], sacc[mt][nt], 0, 0, 0);
        }

        if (dlt == 4 || dlt == -4) {
#pragma unroll
            for (int mt = 0; mt < 4; ++mt)
#pragma unroll
                for (int nt = 0; nt < 4; ++nt)
#pragma unroll
                    for (int r = 0; r < 4; ++r) {
                        int kl = mt * 16 + quad * 4 + r;
                        int ql = nt * 16 + c16;
                        bool ok = (dlt < 0) ? (kl >= ql) : (kl <= ql);
                        if (!ok) sacc[mt][nt][r] = -1e30f;
                    }
        }

        // online softmax (4 q rows per lane), cross-quad reduce
        float pm[4];
#pragma unroll
        for (int nt = 0; nt < 4; ++nt) {
            float a0 = fmaxf(fmaxf(sacc[0][nt][0], sacc[0][nt][1]),
                             fmaxf(sacc[0][nt][2], sacc[0][nt][3]));
            float a1 = fmaxf(fmaxf(sacc[1][nt][0], sacc[1][nt][1]),
                             fmaxf(sacc[1][nt][2], sacc[1][nt][3]));
            float a2 = fmaxf(fmaxf(sacc[2][nt][0], sacc[2][nt][1]),
                             fmaxf(sacc[2][nt][2], sacc[2][nt][3]));
            float a3 = fmaxf(fmaxf(sacc[3][nt][0], sacc[3][nt][1]),
                             fmaxf(sacc[3][nt][2], sacc[3][nt][3]));
            pm[nt] = fmaxf(fmaxf(a0, a1), fmaxf(a2, a3));
            pm[nt] = fmaxf(pm[nt], __shfl_xor(pm[nt], 16, 64));
            pm[nt] = fmaxf(pm[nt], __shfl_xor(pm[nt], 32, 64));
        }
        float al[4];
#pragma unroll
        for (int nt = 0; nt < 4; ++nt) {
            float mn = fmaxf(mrow[nt], pm[nt]);
            al[nt] = exp2f((mrow[nt] - mn) * CC);
            mrow[nt] = mn;
        }
        float ps[4] = {0.f, 0.f, 0.f, 0.f};
#pragma unroll
        for (int mt = 0; mt < 4; ++mt)
#pragma unroll
            for (int nt = 0; nt < 4; ++nt)
#pragma unroll
                for (int r = 0; r < 4; ++r) {
                    float p = exp2f((sacc[mt][nt][r] - mrow[nt]) * CC);
                    sacc[mt][nt][r] = p;
                    ps[nt] += p;
                }
#pragma unroll
        for (int nt = 0; nt < 4; ++nt) {
            ps[nt] += __shfl_xor(ps[nt], 16, 64);
            ps[nt] += __shfl_xor(ps[nt], 32, 64);
            lsum[nt] = lsum[nt] * al[nt] + ps[nt];
        }

        // P -> LDS, granule-swizzled: col = ((key>>3) ^ (row&3))*8 + (key&7)
#pragma unroll
        for (int mt = 0; mt < 4; ++mt)
#pragma unroll
            for (int nt = 0; nt < 4; ++nt) {
                int row = nt * 16 + c16;
                int g   = (2 * mt + (quad >> 1)) ^ (row & 3);
                union { ushort u[4]; uint2 d; } t;
#pragma unroll
                for (int r = 0; r < 4; ++r) t.u[r] = f2bf(sacc[mt][nt][r]);
                *(uint2*)&sP[row * 72 + g * 8 + (quad & 1) * 4] = t.d;
            }

        // rescale O^T
#pragma unroll
        for (int dt = 0; dt < 4; ++dt)
#pragma unroll
            for (int nq = 0; nq < 4; ++nq)
#pragma unroll
                for (int r = 0; r < 4; ++r)
                    oacc[dt][nq][r] *= al[nq];

        // O^T += V^T · P^T  (vf straight from global vT; pf swizzled LDS)
#pragma unroll
        for (int ks = 0; ks < 2; ++ks) {
            bfrag8 vf[4], pf[4];
#pragma unroll
            for (int dt = 0; dt < 4; ++dt)
                vf[dt] = *(const bfrag8*)(vT + vT_b +
                    (size_t)(dt * 16 + c16) * SS + st * 64 + ks * 32 + quad * 8);
#pragma unroll
            for (int nq = 0; nq < 4; ++nq) {
                int row = nq * 16 + c16;
                int g   = (4 * ks + quad) ^ (row & 3);
                pf[nq] = *(const bfrag8*)&sP[row * 72 + g * 8];
            }
#pragma unroll
            for (int dt = 0; dt < 4; ++dt)
#pragma unroll
                for (int nq = 0; nq < 4; ++nq)
                    oacc[dt][nq] = __builtin_amdgcn_mfma_f32_16x16x32_bf16(
                        vf[dt], pf[nq], oacc[dt][nq], 0, 0, 0);
        }
    }

    // normalize + store (lane's 4 regs contiguous in d -> uint2)
#pragma unroll
    for (int nq = 0; nq < 4; ++nq) {
        float inv = 1.f / lsum[nq];
        size_t rbase = ((size_t)b * SS + qt * 64 + nq * 16 + c16) * DD + h * HDIM;
#pragma unroll
        for (int dt = 0; dt < 4; ++dt) {
            union { ushort u[4]; uint2 d; } t;
#pragma unroll
            for (int r = 0; r < 4; ++r) t.u[r] = f2bf(oacc[dt][nq][r] * inv);
            *(uint2*)(out + rbase + dt * 16 + quad * 4) = t.d;
        }
    }
}

// ---------------------------------------------------------------------------
// out = LayerNorm(a + res) * g + b    (one block per row of D=1024)
// ---------------------------------------------------------------------------
__device__ __forceinline__ float ldv(const float* p)  { return *p; }
__device__ __forceinline__ float ldv(const ushort* p) { return bf2f(*p); }
__device__ __forceinline__ void  stv(float* p, float v)  { *p = v; }
__device__ __forceinline__ void  stv(ushort* p, float v) { *p = f2bf(v); }

template <typename RT, typename OT>
__global__ __launch_bounds__(256) void add_ln(
    const ushort* __restrict__ a, const RT* __restrict__ res,
    const float* __restrict__ g, const float* __restrict__ bb,
    OT* __restrict__ out)
{
    const int row = blockIdx.x;
    const int tid = threadIdx.x;
    const size_t base = (size_t)row * DD + tid * 4;

    float x[4];
    float s1 = 0.f, s2 = 0.f;
#pragma unroll
    for (int e = 0; e < 4; ++e) {
        x[e] = bf2f(a[base + e]) + ldv(res + base + e);
        s1 += x[e];
        s2 += x[e] * x[e];
    }
#pragma unroll
    for (int off = 32; off > 0; off >>= 1) {
        s1 += __shfl_down(s1, off, 64);
        s2 += __shfl_down(s2, off, 64);
    }
    __shared__ float r1[4], r2[4];
    const int wave = tid >> 6, lane = tid & 63;
    if (lane == 0) { r1[wave] = s1; r2[wave] = s2; }
    __syncthreads();
    float t1 = r1[0] + r1[1] + r1[2] + r1[3];
    float t2 = r2[0] + r2[1] + r2[2] + r2[3];
    float mu  = t1 * (1.f / DD);
    float var = t2 * (1.f / DD) - mu * mu;
    float rs  = rsqrtf(var + 1e-5f);

#pragma unroll
    for (int e = 0; e < 4; ++e) {
        int col = tid * 4 + e;
        float y = (x[e] - mu) * rs * g[col] + bb[col];
        stv(out + base + e, y);
    }
}

// ---------------------------------------------------------------------------
extern "C" void kernel_launch(void* const* d_in, const int* in_sizes, int n_in,
                              void* d_out, int out_size, void* d_ws, size_t ws_size,
                              hipStream_t stream)
{
    (void)in_sizes; (void)n_in; (void)out_size; (void)ws_size;

    const float* x  = (const float*)d_in[0];
    const float* Wq = (const float*)d_in[1];
    const float* bq = (const float*)d_in[2];
    const float* Wk = (const float*)d_in[3];
    const float* bk = (const float*)d_in[4];
    const float* Wv = (const float*)d_in[5];
    const float* bv = (const float*)d_in[6];
    const float* Wo = (const float*)d_in[7];
    const float* bo = (const float*)d_in[8];
    const float* g1 = (const float*)d_in[9];
    const float* b1 = (const float*)d_in[10];
    const float* W1 = (const float*)d_in[11];
    const float* c1 = (const float*)d_in[12];
    const float* W2 = (const float*)d_in[13];
    const float* c2 = (const float*)d_in[14];
    const float* g2 = (const float*)d_in[15];
    const float* b2 = (const float*)d_in[16];
    float* outp = (float*)d_out;

    char* ws = (char*)d_ws;
    const size_t MB = 1024 * 1024;
    // bf16 workspace (peak 120 MiB with reuse):
    ushort* WqkvT = (ushort*)(ws);            // [  0,  6): Wq^T|Wk^T|Wv^T [3072][1024]
    ushort* WoT = (ushort*)(ws + 6  * MB);    // [  6,  8)
    ushort* W1t = (ushort*)(ws + 8  * MB);    // [  8, 16)  [4096][1024]
    ushort* W2t = (ushort*)(ws + 16 * MB);    // [ 16, 24)  [1024][4096]
    ushort* xb  = (ushort*)(ws + 24 * MB);    // [ 24, 40)
    ushort* qb  = (ushort*)(ws + 40 * MB);    // [ 40, 56)
    ushort* kb  = (ushort*)(ws + 56 * MB);    // [ 56, 72)
    ushort* vT  = (ushort*)(ws + 72 * MB);    // [ 72, 88)  [b][h][64][4096]
    ushort* att = (ushort*)(ws + 88 * MB);    // [ 88,104)
    ushort* aproj = qb;                       // qb dead after attn
    ushort* hbuf  = att;                      // att dead after Wo-gemm
    ushort* m1  = (ushort*)(ws + 24 * MB);    // [ 24, 88): xb/qb/kb/vT dead
    ushort* fbuf = (ushort*)(ws + 104 * MB);  // [104,120)

    dim3 blk(256, 1, 1);
    dim3 gD(DD / 128, MROWS / 128, 1);        // 8 x 64
    dim3 gQKV(3 * DD / 128, MROWS / 128, 1);  // 24 x 64
    dim3 gF(FF / 128, MROWS / 128, 1);        // 32 x 64
    dim3 ga(SS / 64, HH, BB);                 // 64 x 16 x 2, 64-thread blocks
    dim3 gl(MROWS, 1, 1);

    // weight transpose-converts ([K][N] f32 -> [N][K] bf16) + x convert
    hipLaunchKernelGGL(cvt_transpose, dim3(32, 32),  blk, 0, stream, Wq, WqkvT, DD, DD);
    hipLaunchKernelGGL(cvt_transpose, dim3(32, 32),  blk, 0, stream, Wk, WqkvT + 1024 * 1024, DD, DD);
    hipLaunchKernelGGL(cvt_transpose, dim3(32, 32),  blk, 0, stream, Wv, WqkvT + 2 * 1024 * 1024, DD, DD);
    hipLaunchKernelGGL(cvt_transpose, dim3(32, 32),  blk, 0, stream, Wo, WoT, DD, DD);
    hipLaunchKernelGGL(cvt_transpose, dim3(128, 32), blk, 0, stream, W1, W1t, DD, FF);
    hipLaunchKernelGGL(cvt_transpose, dim3(32, 128), blk, 0, stream, W2, W2t, FF, DD);
    hipLaunchKernelGGL(cvt_f32_bf16, dim3(8192), blk, 0, stream, x, xb);

    // fused QKV projection (v written transposed)
    hipLaunchKernelGGL(gemm_qkv, gQKV, blk, 0, stream, xb, WqkvT, bq, bk, bv, qb, kb, vT);

    hipLaunchKernelGGL(attn_flash, ga, dim3(64, 1, 1), 0, stream, qb, kb, vT, att);

    hipLaunchKernelGGL(gemm_bt, gD, blk, 0, stream, att, WoT, bo, aproj, MROWS, DD, DD, 0);
    hipLaunchKernelGGL((add_ln<float, ushort>), gl, blk, 0, stream, aproj, x, g1, b1, hbuf);

    hipLaunchKernelGGL(gemm_bt, gF, blk, 0, stream, hbuf, W1t, c1, m1, MROWS, FF, DD, 1);
    hipLaunchKernelGGL(gemm_bt, gD, blk, 0, stream, m1, W2t, c2, fbuf, MROWS, DD, FF, 0);
    hipLaunchKernelGGL((add_ln<ushort, float>), gl, blk, 0, stream, fbuf, hbuf, g2, b2, outp);
}

// Round 5
// 573.806 us; speedup vs baseline: 2.5194x; 1.0192x over previous
//
#include <hip/hip_runtime.h>
#include <hip/hip_bf16.h>

#define BB 2
#define SS 4096
#define DD 1024
#define HH 16
#define WW 256
#define FF 4096
#define HDIM 64
#define NBLK (SS / WW)       /* 16 */
#define MROWS (BB * SS)      /* 8192 */

typedef short bfrag8 __attribute__((ext_vector_type(8)));
typedef float floatx4 __attribute__((ext_vector_type(4)));

__device__ __forceinline__ float bf2f(ushort u) {
    union { uint i; float f; } c; c.i = ((uint)u) << 16; return c.f;
}
__device__ __forceinline__ ushort f2bf(float f) {
    union { float f; uint i; } c; c.f = f;
    uint r = (c.i + 0x7FFFu + ((c.i >> 16) & 1u)) >> 16;
    return (ushort)r;
}
// gelu(tanh approx) == x * sigmoid(2z), z = 0.79788456(x + 0.044715 x^3)
__device__ __forceinline__ float gelu_fast(float x) {
    float z2 = 1.5957691216057308f * x * (1.f + 0.044715f * x * x); // 2z
    return x / (1.f + __expf(-z2));
}

// async global->LDS, 16B per lane. LDS dest must be contiguous in lane order.
__device__ __forceinline__ void gload_lds16(const ushort* g, ushort* l) {
    __builtin_amdgcn_global_load_lds(
        (const __attribute__((address_space(1))) void*)g,
        (__attribute__((address_space(3))) void*)l, 16, 0, 0);
}

// ---------------------------------------------------------------------------
// f32 -> bf16 bulk convert (grid * 1024 elements)
// ---------------------------------------------------------------------------
__global__ __launch_bounds__(256) void cvt_f32_bf16(
    const float* __restrict__ in, ushort* __restrict__ out)
{
    size_t i = ((size_t)blockIdx.x * 256 + threadIdx.x) * 4;
    float4 v = *(const float4*)(in + i);
    union { ushort u[4]; uint2 d; } t;
    t.u[0] = f2bf(v.x); t.u[1] = f2bf(v.y);
    t.u[2] = f2bf(v.z); t.u[3] = f2bf(v.w);
    *(uint2*)(out + i) = t.d;
}

// ---------------------------------------------------------------------------
// Fused transpose-convert of ALL weights: f32 [K][N] -> bf16 [N][K].
// grid = (128, 32, 6); z selects the weight. 32x32 LDS tiles.
// ---------------------------------------------------------------------------
__global__ __launch_bounds__(256) void cvt_transpose_all(
    const float* __restrict__ Wq, const float* __restrict__ Wk,
    const float* __restrict__ Wv, const float* __restrict__ Wo,
    const float* __restrict__ W1, const float* __restrict__ W2,
    ushort* __restrict__ WqkvT, ushort* __restrict__ WoT,
    ushort* __restrict__ W1t, ushort* __restrict__ W2t)
{
    __shared__ ushort sT[32][33];
    const int z = blockIdx.z;
    const float* in; ushort* out; int K, N, n0, k0;
    if (z < 4) {
        if (blockIdx.x >= 32) return;
        in  = (z == 0) ? Wq : (z == 1) ? Wk : (z == 2) ? Wv : Wo;
        out = (z < 3) ? WqkvT + (size_t)z * 1024 * 1024 : WoT;
        K = 1024; N = 1024;
        n0 = blockIdx.x * 32; k0 = blockIdx.y * 32;
    } else if (z == 4) {
        in = W1; out = W1t; K = 1024; N = 4096;
        n0 = blockIdx.x * 32; k0 = blockIdx.y * 32;
    } else {
        in = W2; out = W2t; K = 4096; N = 1024;
        n0 = blockIdx.y * 32; k0 = blockIdx.x * 32;
    }

    const int r  = threadIdx.x >> 3;        // 0..31
    const int c4 = (threadIdx.x & 7) * 4;   // 0..28

    float4 v = *(const float4*)(in + (size_t)(k0 + r) * N + n0 + c4);
    sT[c4 + 0][r] = f2bf(v.x);
    sT[c4 + 1][r] = f2bf(v.y);
    sT[c4 + 2][r] = f2bf(v.z);
    sT[c4 + 3][r] = f2bf(v.w);
    __syncthreads();
    union { ushort u[4]; uint2 d; } t;
#pragma unroll
    for (int e = 0; e < 4; ++e) t.u[e] = sT[r][c4 + e];
    *(uint2*)(out + (size_t)(n0 + r) * K + k0 + c4) = t.d;
}

// ---------------------------------------------------------------------------
// GEMM: C[M,N] = A[M,K] @ B[K,N] + bias[N], Bt = B^T [N][K] bf16.
// m97 structure: 128x128 tile, BK=32, global_load_lds width-16 staging.
// MFMA operands SWAPPED (weights as A-operand) so each lane's 4 acc regs are
// contiguous in N -> packed uint2 stores (16 instead of 64 scalar stores).
// ---------------------------------------------------------------------------
__global__ __launch_bounds__(256) void gemm_bt(
    const ushort* __restrict__ A, const ushort* __restrict__ Bt,
    const float* __restrict__ bias, ushort* __restrict__ C,
    int M, int N, int K, int act)
{
    __shared__ ushort sA[128 * 32];
    __shared__ ushort sB[128 * 32];

    const int tid  = threadIdx.x;
    const int m0   = blockIdx.y * 128;
    const int n0   = blockIdx.x * 128;
    const int wave = tid >> 6;
    const int lane = tid & 63;
    const int wm   = (wave >> 1) * 64;
    const int wn   = (wave & 1) * 64;
    const int lrow = lane & 15;
    const int quad = lane >> 4;

    floatx4 acc[4][4];
#pragma unroll
    for (int i = 0; i < 4; ++i)
#pragma unroll
        for (int j = 0; j < 4; ++j)
            acc[i][j] = (floatx4){0.f, 0.f, 0.f, 0.f};

    for (int k0 = 0; k0 < K; k0 += 32) {
#pragma unroll
        for (int it = 0; it < 2; ++it) {
            int c = it * 256 + tid;
            gload_lds16(A  + (size_t)(m0 + (c >> 2)) * K + k0 + (c & 3) * 8, &sA[c * 8]);
            gload_lds16(Bt + (size_t)(n0 + (c >> 2)) * K + k0 + (c & 3) * 8, &sB[c * 8]);
        }
        __syncthreads();

        bfrag8 af[4], bfv[4];
#pragma unroll
        for (int mt = 0; mt < 4; ++mt)
            af[mt] = *(const bfrag8*)&sA[(wm + mt * 16 + lrow) * 32 + quad * 8];
#pragma unroll
        for (int nt = 0; nt < 4; ++nt)
            bfv[nt] = *(const bfrag8*)&sB[(wn + nt * 16 + lrow) * 32 + quad * 8];
        // swapped: D[n][m] -> lane col = m, regs span n (contiguous)
#pragma unroll
        for (int mt = 0; mt < 4; ++mt)
#pragma unroll
            for (int nt = 0; nt < 4; ++nt)
                acc[mt][nt] = __builtin_amdgcn_mfma_f32_16x16x32_bf16(
                    bfv[nt], af[mt], acc[mt][nt], 0, 0, 0);
        __syncthreads();
    }

    // epilogue: m = m0+wm+mt*16+lrow (lane), n-chunk = n0+wn+nt*16+quad*4 (regs)
#pragma unroll
    for (int nt = 0; nt < 4; ++nt) {
        int nb = n0 + wn + nt * 16 + quad * 4;
        union { float4 v; float f[4]; } b4;
        b4.v = *(const float4*)(bias + nb);
#pragma unroll
        for (int mt = 0; mt < 4; ++mt) {
            int row = m0 + wm + mt * 16 + lrow;
            union { ushort u[4]; uint2 d; } t;
#pragma unroll
            for (int r = 0; r < 4; ++r) {
                float v = acc[mt][nt][r] + b4.f[r];
                if (act) v = gelu_fast(v);
                t.u[r] = f2bf(v);
            }
            *(uint2*)(C + (size_t)row * N + nb) = t.d;
        }
    }
}

// ---------------------------------------------------------------------------
// Fused QKV GEMM: A[8192][1024] @ [Wq|Wk|Wv] (Bt = [3072][1024]).
// cols [0,1024) -> qb; [1024,2048) -> kb (both swapped-operand, uint2 stores);
// [2048,3072) -> vT [b][h][dh][s] (unswapped: regs contiguous in s).
// ---------------------------------------------------------------------------
__global__ __launch_bounds__(256) void gemm_qkv(
    const ushort* __restrict__ A, const ushort* __restrict__ Bt,
    const float* __restrict__ bq, const float* __restrict__ bk,
    const float* __restrict__ bv,
    ushort* __restrict__ qb, ushort* __restrict__ kb, ushort* __restrict__ vT)
{
    __shared__ ushort sA[128 * 32];
    __shared__ ushort sB[128 * 32];
    const int K = DD;

    const int tid  = threadIdx.x;
    const int m0   = blockIdx.y * 128;
    const int n0   = blockIdx.x * 128;
    const int wave = tid >> 6;
    const int lane = tid & 63;
    const int wm   = (wave >> 1) * 64;
    const int wn   = (wave & 1) * 64;
    const int lrow = lane & 15;
    const int quad = lane >> 4;
    const int sel  = n0 >> 10;               // block-uniform: 0=q 1=k 2=v

    floatx4 acc[4][4];
#pragma unroll
    for (int i = 0; i < 4; ++i)
#pragma unroll
        for (int j = 0; j < 4; ++j)
            acc[i][j] = (floatx4){0.f, 0.f, 0.f, 0.f};

    if (sel < 2) {
        for (int k0 = 0; k0 < K; k0 += 32) {
#pragma unroll
            for (int it = 0; it < 2; ++it) {
                int c = it * 256 + tid;
                gload_lds16(A  + (size_t)(m0 + (c >> 2)) * K + k0 + (c & 3) * 8, &sA[c * 8]);
                gload_lds16(Bt + (size_t)(n0 + (c >> 2)) * K + k0 + (c & 3) * 8, &sB[c * 8]);
            }
            __syncthreads();
            bfrag8 af[4], bfv[4];
#pragma unroll
            for (int mt = 0; mt < 4; ++mt)
                af[mt] = *(const bfrag8*)&sA[(wm + mt * 16 + lrow) * 32 + quad * 8];
#pragma unroll
            for (int nt = 0; nt < 4; ++nt)
                bfv[nt] = *(const bfrag8*)&sB[(wn + nt * 16 + lrow) * 32 + quad * 8];
#pragma unroll
            for (int mt = 0; mt < 4; ++mt)
#pragma unroll
                for (int nt = 0; nt < 4; ++nt)
                    acc[mt][nt] = __builtin_amdgcn_mfma_f32_16x16x32_bf16(
                        bfv[nt], af[mt], acc[mt][nt], 0, 0, 0);
            __syncthreads();
        }
        ushort* C = (sel == 0) ? qb : kb;
        const float* bias = (sel == 0) ? bq : bk;
        const int colbase = n0 + wn;
#pragma unroll
        for (int nt = 0; nt < 4; ++nt) {
            int nb = (colbase + nt * 16 + quad * 4) & 1023;
            union { float4 v; float f[4]; } b4;
            b4.v = *(const float4*)(bias + nb);
#pragma unroll
            for (int mt = 0; mt < 4; ++mt) {
                int row = m0 + wm + mt * 16 + lrow;
                union { ushort u[4]; uint2 d; } t;
#pragma unroll
                for (int r = 0; r < 4; ++r) t.u[r] = f2bf(acc[mt][nt][r] + b4.f[r]);
                *(uint2*)(C + (size_t)row * DD + nb) = t.d;
            }
        }
    } else {
        for (int k0 = 0; k0 < K; k0 += 32) {
#pragma unroll
            for (int it = 0; it < 2; ++it) {
                int c = it * 256 + tid;
                gload_lds16(A  + (size_t)(m0 + (c >> 2)) * K + k0 + (c & 3) * 8, &sA[c * 8]);
                gload_lds16(Bt + (size_t)(n0 + (c >> 2)) * K + k0 + (c & 3) * 8, &sB[c * 8]);
            }
            __syncthreads();
            bfrag8 af[4], bfv[4];
#pragma unroll
            for (int mt = 0; mt < 4; ++mt)
                af[mt] = *(const bfrag8*)&sA[(wm + mt * 16 + lrow) * 32 + quad * 8];
#pragma unroll
            for (int nt = 0; nt < 4; ++nt)
                bfv[nt] = *(const bfrag8*)&sB[(wn + nt * 16 + lrow) * 32 + quad * 8];
#pragma unroll
            for (int mt = 0; mt < 4; ++mt)
#pragma unroll
                for (int nt = 0; nt < 4; ++nt)
                    acc[mt][nt] = __builtin_amdgcn_mfma_f32_16x16x32_bf16(
                        af[mt], bfv[nt], acc[mt][nt], 0, 0, 0);
            __syncthreads();
        }
        const int colbase = n0 + wn;
        // vT[b][h][dh][s]; lane's 4 acc regs contiguous in s -> uint2
#pragma unroll
        for (int nt = 0; nt < 4; ++nt) {
            int cc = (colbase + nt * 16 + lrow) & 1023;
            int h = cc >> 6, dh = cc & 63;
            float bb = bv[cc];
#pragma unroll
            for (int mt = 0; mt < 4; ++mt) {
                int row0 = m0 + wm + mt * 16 + (quad << 2);
                int b = row0 >> 12, s = row0 & 4095;
                union { ushort u[4]; uint2 d; } t;
#pragma unroll
                for (int r = 0; r < 4; ++r) t.u[r] = f2bf(acc[mt][nt][r] + bb);
                *(uint2*)(vT + (size_t)(((b * HH + h) * HDIM + dh)) * SS + s) = t.d;
            }
        }
    }
}

// ---------------------------------------------------------------------------
// Barrier-free MFMA flash attention. One wave per block; block = (qt, h, b).
// S^T = K·Q^T -> online softmax -> P via swizzled LDS -> O^T += V^T·P^T
// (V^T straight from global vT). No __syncthreads.
// ---------------------------------------------------------------------------
__global__ __launch_bounds__(64, 2) void attn_flash(
    const ushort* __restrict__ q, const ushort* __restrict__ k,
    const ushort* __restrict__ vT, ushort* __restrict__ out)
{
    __shared__ ushort sP[64 * 72];

    const int qt = blockIdx.x, h = blockIdx.y, b = blockIdx.z;
    const int lane = threadIdx.x;
    const int c16  = lane & 15;
    const int quad = lane >> 4;
    const float CC = 0.18033688011112042f;   // (1/sqrt(64)) * log2(e)

    bfrag8 qf[4][2];
    {
        const size_t qbase = ((size_t)b * SS + qt * 64) * DD + h * HDIM;
#pragma unroll
        for (int nt = 0; nt < 4; ++nt)
#pragma unroll
            for (int ks = 0; ks < 2; ++ks)
                qf[nt][ks] = *(const bfrag8*)(q + qbase +
                    (size_t)(nt * 16 + c16) * DD + ks * 32 + quad * 8);
    }

    floatx4 oacc[4][4];
#pragma unroll
    for (int i = 0; i < 4; ++i)
#pragma unroll
        for (int j = 0; j < 4; ++j)
            oacc[i][j] = (floatx4){0.f, 0.f, 0.f, 0.f};
    float mrow[4], lsum[4];
#pragma unroll
    for (int i = 0; i < 4; ++i) { mrow[i] = -1e30f; lsum[i] = 0.f; }

    const int st0 = (qt - 4 > 0) ? qt - 4 : 0;
    const int st1 = (qt + 4 < 63) ? qt + 4 : 63;
    const size_t kb_b  = (size_t)b * SS * DD + h * HDIM;
    const size_t vT_b  = (size_t)((b * HH + h) * HDIM) * SS;

    for (int st = st0; st <= st1; ++st) {
        const int dlt = st - qt;

        floatx4 sacc[4][4];
#pragma unroll
        for (int i = 0; i < 4; ++i)
#pragma unroll
            for (int j = 0; j < 4; ++j)
                sacc[i][j] = (floatx4){0.f, 0.f, 0.f, 0.f};
#pragma unroll
        for (int ks = 0; ks < 2; ++ks) {
            bfrag8 kf[4];
#pragma unroll
            for (int mt = 0; mt < 4; ++mt)
                kf[mt] = *(const bfrag8*)(k + kb_b +
                    (size_t)(st * 64 + mt * 16 + c16) * DD + ks * 32 + quad * 8);
#pragma unroll
            for (int mt = 0; mt < 4; ++mt)
#pragma unroll
                for (int nt = 0; nt < 4; ++nt)
                    sacc[mt][nt] = __builtin_amdgcn_mfma_f32_16x16x32_bf16(
                        kf[mt], qf[nt][ks], sacc[mt][nt], 0, 0, 0);
        }

        if (dlt == 4 || dlt == -4) {
#pragma unroll
            for (int mt = 0; mt < 4; ++mt)
#pragma unroll
                for (int nt = 0; nt < 4; ++nt)
#pragma unroll
                    for (int r = 0; r < 4; ++r) {
                        int kl = mt * 16 + quad * 4 + r;
                        int ql = nt * 16 + c16;
                        bool ok = (dlt < 0) ? (kl >= ql) : (kl <= ql);
                        if (!ok) sacc[mt][nt][r] = -1e30f;
                    }
        }

        float pm[4];
#pragma unroll
        for (int nt = 0; nt < 4; ++nt) {
            float a0 = fmaxf(fmaxf(sacc[0][nt][0], sacc[0][nt][1]),
                             fmaxf(sacc[0][nt][2], sacc[0][nt][3]));
            float a1 = fmaxf(fmaxf(sacc[1][nt][0], sacc[1][nt][1]),
                             fmaxf(sacc[1][nt][2], sacc[1][nt][3]));
            float a2 = fmaxf(fmaxf(sacc[2][nt][0], sacc[2][nt][1]),
                             fmaxf(sacc[2][nt][2], sacc[2][nt][3]));
            float a3 = fmaxf(fmaxf(sacc[3][nt][0], sacc[3][nt][1]),
                             fmaxf(sacc[3][nt][2], sacc[3][nt][3]));
            pm[nt] = fmaxf(fmaxf(a0, a1), fmaxf(a2, a3));
            pm[nt] = fmaxf(pm[nt], __shfl_xor(pm[nt], 16, 64));
            pm[nt] = fmaxf(pm[nt], __shfl_xor(pm[nt], 32, 64));
        }
        float al[4];
#pragma unroll
        for (int nt = 0; nt < 4; ++nt) {
            float mn = fmaxf(mrow[nt], pm[nt]);
            al[nt] = exp2f((mrow[nt] - mn) * CC);
            mrow[nt] = mn;
        }
        float ps[4] = {0.f, 0.f, 0.f, 0.f};
#pragma unroll
        for (int mt = 0; mt < 4; ++mt)
#pragma unroll
            for (int nt = 0; nt < 4; ++nt)
#pragma unroll
                for (int r = 0; r < 4; ++r) {
                    float p = exp2f((sacc[mt][nt][r] - mrow[nt]) * CC);
                    sacc[mt][nt][r] = p;
                    ps[nt] += p;
                }
#pragma unroll
        for (int nt = 0; nt < 4; ++nt) {
            ps[nt] += __shfl_xor(ps[nt], 16, 64);
            ps[nt] += __shfl_xor(ps[nt], 32, 64);
            lsum[nt] = lsum[nt] * al[nt] + ps[nt];
        }

#pragma unroll
        for (int mt = 0; mt < 4; ++mt)
#pragma unroll
            for (int nt = 0; nt < 4; ++nt) {
                int row = nt * 16 + c16;
                int g   = (2 * mt + (quad >> 1)) ^ (row & 3);
                union { ushort u[4]; uint2 d; } t;
#pragma unroll
                for (int r = 0; r < 4; ++r) t.u[r] = f2bf(sacc[mt][nt][r]);
                *(uint2*)&sP[row * 72 + g * 8 + (quad & 1) * 4] = t.d;
            }

#pragma unroll
        for (int dt = 0; dt < 4; ++dt)
#pragma unroll
            for (int nq = 0; nq < 4; ++nq)
#pragma unroll
                for (int r = 0; r < 4; ++r)
                    oacc[dt][nq][r] *= al[nq];

#pragma unroll
        for (int ks = 0; ks < 2; ++ks) {
            bfrag8 vf[4], pf[4];
#pragma unroll
            for (int dt = 0; dt < 4; ++dt)
                vf[dt] = *(const bfrag8*)(vT + vT_b +
                    (size_t)(dt * 16 + c16) * SS + st * 64 + ks * 32 + quad * 8);
#pragma unroll
            for (int nq = 0; nq < 4; ++nq) {
                int row = nq * 16 + c16;
                int g   = (4 * ks + quad) ^ (row & 3);
                pf[nq] = *(const bfrag8*)&sP[row * 72 + g * 8];
            }
#pragma unroll
            for (int dt = 0; dt < 4; ++dt)
#pragma unroll
                for (int nq = 0; nq < 4; ++nq)
                    oacc[dt][nq] = __builtin_amdgcn_mfma_f32_16x16x32_bf16(
                        vf[dt], pf[nq], oacc[dt][nq], 0, 0, 0);
        }
    }

#pragma unroll
    for (int nq = 0; nq < 4; ++nq) {
        float inv = 1.f / lsum[nq];
        size_t rbase = ((size_t)b * SS + qt * 64 + nq * 16 + c16) * DD + h * HDIM;
#pragma unroll
        for (int dt = 0; dt < 4; ++dt) {
            union { ushort u[4]; uint2 d; } t;
#pragma unroll
            for (int r = 0; r < 4; ++r) t.u[r] = f2bf(oacc[dt][nq][r] * inv);
            *(uint2*)(out + rbase + dt * 16 + quad * 4) = t.d;
        }
    }
}

// ---------------------------------------------------------------------------
// out = LayerNorm(a + res) * g + b    (one block per row of D=1024)
// ---------------------------------------------------------------------------
__device__ __forceinline__ float ldv(const float* p)  { return *p; }
__device__ __forceinline__ float ldv(const ushort* p) { return bf2f(*p); }
__device__ __forceinline__ void  stv(float* p, float v)  { *p = v; }
__device__ __forceinline__ void  stv(ushort* p, float v) { *p = f2bf(v); }

template <typename RT, typename OT>
__global__ __launch_bounds__(256) void add_ln(
    const ushort* __restrict__ a, const RT* __restrict__ res,
    const float* __restrict__ g, const float* __restrict__ bb,
    OT* __restrict__ out)
{
    const int row = blockIdx.x;
    const int tid = threadIdx.x;
    const size_t base = (size_t)row * DD + tid * 4;

    float x[4];
    float s1 = 0.f, s2 = 0.f;
#pragma unroll
    for (int e = 0; e < 4; ++e) {
        x[e] = bf2f(a[base + e]) + ldv(res + base + e);
        s1 += x[e];
        s2 += x[e] * x[e];
    }
#pragma unroll
    for (int off = 32; off > 0; off >>= 1) {
        s1 += __shfl_down(s1, off, 64);
        s2 += __shfl_down(s2, off, 64);
    }
    __shared__ float r1[4], r2[4];
    const int wave = tid >> 6, lane = tid & 63;
    if (lane == 0) { r1[wave] = s1; r2[wave] = s2; }
    __syncthreads();
    float t1 = r1[0] + r1[1] + r1[2] + r1[3];
    float t2 = r2[0] + r2[1] + r2[2] + r2[3];
    float mu  = t1 * (1.f / DD);
    float var = t2 * (1.f / DD) - mu * mu;
    float rs  = rsqrtf(var + 1e-5f);

#pragma unroll
    for (int e = 0; e < 4; ++e) {
        int col = tid * 4 + e;
        float y = (x[e] - mu) * rs * g[col] + bb[col];
        stv(out + base + e, y);
    }
}

// ---------------------------------------------------------------------------
extern "C" void kernel_launch(void* const* d_in, const int* in_sizes, int n_in,
                              void* d_out, int out_size, void* d_ws, size_t ws_size,
                              hipStream_t stream)
{
    (void)in_sizes; (void)n_in; (void)out_size; (void)ws_size;

    const float* x  = (const float*)d_in[0];
    const float* Wq = (const float*)d_in[1];
    const float* bq = (const float*)d_in[2];
    const float* Wk = (const float*)d_in[3];
    const float* bk = (const float*)d_in[4];
    const float* Wv = (const float*)d_in[5];
    const float* bv = (const float*)d_in[6];
    const float* Wo = (const float*)d_in[7];
    const float* bo = (const float*)d_in[8];
    const float* g1 = (const float*)d_in[9];
    const float* b1 = (const float*)d_in[10];
    const float* W1 = (const float*)d_in[11];
    const float* c1 = (const float*)d_in[12];
    const float* W2 = (const float*)d_in[13];
    const float* c2 = (const float*)d_in[14];
    const float* g2 = (const float*)d_in[15];
    const float* b2 = (const float*)d_in[16];
    float* outp = (float*)d_out;

    char* ws = (char*)d_ws;
    const size_t MB = 1024 * 1024;
    ushort* WqkvT = (ushort*)(ws);            // [  0,  6): Wq^T|Wk^T|Wv^T
    ushort* WoT = (ushort*)(ws + 6  * MB);    // [  6,  8)
    ushort* W1t = (ushort*)(ws + 8  * MB);    // [  8, 16)
    ushort* W2t = (ushort*)(ws + 16 * MB);    // [ 16, 24)
    ushort* xb  = (ushort*)(ws + 24 * MB);    // [ 24, 40)
    ushort* qb  = (ushort*)(ws + 40 * MB);    // [ 40, 56)
    ushort* kb  = (ushort*)(ws + 56 * MB);    // [ 56, 72)
    ushort* vT  = (ushort*)(ws + 72 * MB);    // [ 72, 88)  [b][h][64][4096]
    ushort* att = (ushort*)(ws + 88 * MB);    // [ 88,104)
    ushort* aproj = qb;
    ushort* hbuf  = att;
    ushort* m1  = (ushort*)(ws + 24 * MB);    // [ 24, 88)
    ushort* fbuf = (ushort*)(ws + 104 * MB);  // [104,120)

    dim3 blk(256, 1, 1);
    dim3 gD(DD / 128, MROWS / 128, 1);
    dim3 gQKV(3 * DD / 128, MROWS / 128, 1);
    dim3 gF(FF / 128, MROWS / 128, 1);
    dim3 ga(SS / 64, HH, BB);
    dim3 gl(MROWS, 1, 1);

    hipLaunchKernelGGL(cvt_transpose_all, dim3(128, 32, 6), blk, 0, stream,
                       Wq, Wk, Wv, Wo, W1, W2, WqkvT, WoT, W1t, W2t);
    hipLaunchKernelGGL(cvt_f32_bf16, dim3(8192), blk, 0, stream, x, xb);

    hipLaunchKernelGGL(gemm_qkv, gQKV, blk, 0, stream, xb, WqkvT, bq, bk, bv, qb, kb, vT);

    hipLaunchKernelGGL(attn_flash, ga, dim3(64, 1, 1), 0, stream, qb, kb, vT, att);

    hipLaunchKernelGGL(gemm_bt, gD, blk, 0, stream, att, WoT, bo, aproj, MROWS, DD, DD, 0);
    hipLaunchKernelGGL((add_ln<float, ushort>), gl, blk, 0, stream, aproj, x, g1, b1, hbuf);

    hipLaunchKernelGGL(gemm_bt, gF, blk, 0, stream, hbuf, W1t, c1, m1, MROWS, FF, DD, 1);
    hipLaunchKernelGGL(gemm_bt, gD, blk, 0, stream, m1, W2t, c2, fbuf, MROWS, DD, FF, 0);
    hipLaunchKernelGGL((add_ln<ushort, float>), gl, blk, 0, stream, fbuf, hbuf, g2, b2, outp);
}

// Round 6
// 491.735 us; speedup vs baseline: 2.9399x; 1.1669x over previous
//
#include <hip/hip_runtime.h>
#include <hip/hip_bf16.h>

#define BB 2
#define SS 4096
#define DD 1024
#define HH 16
#define WW 256
#define FF 4096
#define HDIM 64
#define NBLK (SS / WW)       /* 16 */
#define MROWS (BB * SS)      /* 8192 */

typedef short bfrag8 __attribute__((ext_vector_type(8)));
typedef float floatx4 __attribute__((ext_vector_type(4)));

__device__ __forceinline__ float bf2f(ushort u) {
    union { uint i; float f; } c; c.i = ((uint)u) << 16; return c.f;
}
__device__ __forceinline__ ushort f2bf(float f) {
    union { float f; uint i; } c; c.f = f;
    uint r = (c.i + 0x7FFFu + ((c.i >> 16) & 1u)) >> 16;
    return (ushort)r;
}
// gelu(tanh approx) == x * sigmoid(2z), z = 0.79788456(x + 0.044715 x^3)
__device__ __forceinline__ float gelu_fast(float x) {
    float z2 = 1.5957691216057308f * x * (1.f + 0.044715f * x * x); // 2z
    return x / (1.f + __expf(-z2));
}

// async global->LDS, 16B per lane. LDS dest must be contiguous in lane order.
__device__ __forceinline__ void gload_lds16(const ushort* g, ushort* l) {
    __builtin_amdgcn_global_load_lds(
        (const __attribute__((address_space(1))) void*)g,
        (__attribute__((address_space(3))) void*)l, 16, 0, 0);
}

// ---------------------------------------------------------------------------
// f32 -> bf16 bulk convert (grid * 1024 elements)
// ---------------------------------------------------------------------------
__global__ __launch_bounds__(256) void cvt_f32_bf16(
    const float* __restrict__ in, ushort* __restrict__ out)
{
    size_t i = ((size_t)blockIdx.x * 256 + threadIdx.x) * 4;
    float4 v = *(const float4*)(in + i);
    union { ushort u[4]; uint2 d; } t;
    t.u[0] = f2bf(v.x); t.u[1] = f2bf(v.y);
    t.u[2] = f2bf(v.z); t.u[3] = f2bf(v.w);
    *(uint2*)(out + i) = t.d;
}

// ---------------------------------------------------------------------------
// Fused transpose-convert of ALL weights: f32 [K][N] -> bf16 [N][K].
// grid = (128, 32, 6); z selects the weight. 32x32 LDS tiles.
// ---------------------------------------------------------------------------
__global__ __launch_bounds__(256) void cvt_transpose_all(
    const float* __restrict__ Wq, const float* __restrict__ Wk,
    const float* __restrict__ Wv, const float* __restrict__ Wo,
    const float* __restrict__ W1, const float* __restrict__ W2,
    ushort* __restrict__ WqkvT, ushort* __restrict__ WoT,
    ushort* __restrict__ W1t, ushort* __restrict__ W2t)
{
    __shared__ ushort sT[32][33];
    const int z = blockIdx.z;
    const float* in; ushort* out; int K, N, n0, k0;
    if (z < 4) {
        if (blockIdx.x >= 32) return;
        in  = (z == 0) ? Wq : (z == 1) ? Wk : (z == 2) ? Wv : Wo;
        out = (z < 3) ? WqkvT + (size_t)z * 1024 * 1024 : WoT;
        K = 1024; N = 1024;
        n0 = blockIdx.x * 32; k0 = blockIdx.y * 32;
    } else if (z == 4) {
        in = W1; out = W1t; K = 1024; N = 4096;
        n0 = blockIdx.x * 32; k0 = blockIdx.y * 32;
    } else {
        in = W2; out = W2t; K = 4096; N = 1024;
        n0 = blockIdx.y * 32; k0 = blockIdx.x * 32;
    }

    const int r  = threadIdx.x >> 3;        // 0..31
    const int c4 = (threadIdx.x & 7) * 4;   // 0..28

    float4 v = *(const float4*)(in + (size_t)(k0 + r) * N + n0 + c4);
    sT[c4 + 0][r] = f2bf(v.x);
    sT[c4 + 1][r] = f2bf(v.y);
    sT[c4 + 2][r] = f2bf(v.z);
    sT[c4 + 3][r] = f2bf(v.w);
    __syncthreads();
    union { ushort u[4]; uint2 d; } t;
#pragma unroll
    for (int e = 0; e < 4; ++e) t.u[e] = sT[r][c4 + e];
    *(uint2*)(out + (size_t)(n0 + r) * K + k0 + c4) = t.d;
}

// ---------------------------------------------------------------------------
// GEMM: C[M,N] = A[M,K] @ B[K,N] + bias[N], Bt = B^T [N][K] bf16.
// 128x128 tile, BK=64, global_load_lds width-16 staging with XOR-swizzled
// k-granules (source-column permute keeps DMA dest lane-contiguous; LDS reads
// land ~2-way on banks). 1D grid with XCD-aware mapping: consecutive blocks
// of one XCD sweep x fastest within a contiguous y range -> A-panel L2 reuse.
// MFMA operands swapped (weights as A-operand) -> packed uint2 stores.
// ---------------------------------------------------------------------------
__global__ __launch_bounds__(256) void gemm_bt(
    const ushort* __restrict__ A, const ushort* __restrict__ Bt,
    const float* __restrict__ bias, ushort* __restrict__ C,
    int M, int N, int K, int act)
{
    __shared__ ushort sA[128 * 64];
    __shared__ ushort sB[128 * 64];

    const int tid  = threadIdx.x;
    const int nx   = N >> 7;
    const int nyg  = (M >> 7) >> 3;          // y-panels per XCD
    const int gid  = blockIdx.x;
    const int j    = gid >> 3;
    const int m0   = ((gid & 7) * nyg + j / nx) * 128;
    const int n0   = (j % nx) * 128;
    const int wave = tid >> 6;
    const int lane = tid & 63;
    const int wm   = (wave >> 1) * 64;
    const int wn   = (wave & 1) * 64;
    const int lrow = lane & 15;
    const int quad = lane >> 4;

    floatx4 acc[4][4];
#pragma unroll
    for (int i = 0; i < 4; ++i)
#pragma unroll
        for (int j2 = 0; j2 < 4; ++j2)
            acc[i][j2] = (floatx4){0.f, 0.f, 0.f, 0.f};

    for (int k0 = 0; k0 < K; k0 += 64) {
#pragma unroll
        for (int it = 0; it < 4; ++it) {
            int c    = it * 256 + tid;            // 0..1023 chunks of 16B
            int row  = c >> 3;
            int scol = ((c ^ (row & 7)) & 7) << 3;  // XOR-swizzled source col
            gload_lds16(A  + (size_t)(m0 + row) * K + k0 + scol, &sA[c * 8]);
            gload_lds16(Bt + (size_t)(n0 + row) * K + k0 + scol, &sB[c * 8]);
        }
        __syncthreads();

#pragma unroll
        for (int ks = 0; ks < 2; ++ks) {
            bfrag8 af[4], bfv[4];
#pragma unroll
            for (int mt = 0; mt < 4; ++mt) {
                int row = wm + mt * 16 + lrow;
                int G   = ks * 4 + quad;
                af[mt] = *(const bfrag8*)&sA[row * 64 + (((G ^ row) & 7) << 3) + ((G >> 3) << 6)];
            }
#pragma unroll
            for (int nt = 0; nt < 4; ++nt) {
                int row = wn + nt * 16 + lrow;
                int G   = ks * 4 + quad;
                bfv[nt] = *(const bfrag8*)&sB[row * 64 + (((G ^ row) & 7) << 3) + ((G >> 3) << 6)];
            }
#pragma unroll
            for (int mt = 0; mt < 4; ++mt)
#pragma unroll
                for (int nt = 0; nt < 4; ++nt)
                    acc[mt][nt] = __builtin_amdgcn_mfma_f32_16x16x32_bf16(
                        bfv[nt], af[mt], acc[mt][nt], 0, 0, 0);
        }
        __syncthreads();
    }

    // epilogue: m = m0+wm+mt*16+lrow (lane), n-chunk = n0+wn+nt*16+quad*4 (regs)
#pragma unroll
    for (int nt = 0; nt < 4; ++nt) {
        int nb = n0 + wn + nt * 16 + quad * 4;
        union { float4 v; float f[4]; } b4;
        b4.v = *(const float4*)(bias + nb);
#pragma unroll
        for (int mt = 0; mt < 4; ++mt) {
            int row = m0 + wm + mt * 16 + lrow;
            union { ushort u[4]; uint2 d; } t;
#pragma unroll
            for (int r = 0; r < 4; ++r) {
                float v = acc[mt][nt][r] + b4.f[r];
                if (act) v = gelu_fast(v);
                t.u[r] = f2bf(v);
            }
            *(uint2*)(C + (size_t)row * N + nb) = t.d;
        }
    }
}

// ---------------------------------------------------------------------------
// Fused QKV GEMM: A[8192][1024] @ [Wq|Wk|Wv] (Bt = [3072][1024]), BK=64,
// swizzled staging, XCD-aware 1D grid (1536 blocks). cols [0,1024) -> qb;
// [1024,2048) -> kb (swapped-operand); [2048,3072) -> vT [b][h][dh][s].
// ---------------------------------------------------------------------------
__global__ __launch_bounds__(256) void gemm_qkv(
    const ushort* __restrict__ A, const ushort* __restrict__ Bt,
    const float* __restrict__ bq, const float* __restrict__ bk,
    const float* __restrict__ bv,
    ushort* __restrict__ qb, ushort* __restrict__ kb, ushort* __restrict__ vT)
{
    __shared__ ushort sA[128 * 64];
    __shared__ ushort sB[128 * 64];
    const int K = DD;

    const int tid  = threadIdx.x;
    const int nx   = 24, nyg = 8;
    const int gid  = blockIdx.x;
    const int j    = gid >> 3;
    const int m0   = ((gid & 7) * nyg + j / nx) * 128;
    const int n0   = (j % nx) * 128;
    const int wave = tid >> 6;
    const int lane = tid & 63;
    const int wm   = (wave >> 1) * 64;
    const int wn   = (wave & 1) * 64;
    const int lrow = lane & 15;
    const int quad = lane >> 4;
    const int sel  = n0 >> 10;               // block-uniform: 0=q 1=k 2=v

    floatx4 acc[4][4];
#pragma unroll
    for (int i = 0; i < 4; ++i)
#pragma unroll
        for (int j2 = 0; j2 < 4; ++j2)
            acc[i][j2] = (floatx4){0.f, 0.f, 0.f, 0.f};

    for (int k0 = 0; k0 < K; k0 += 64) {
#pragma unroll
        for (int it = 0; it < 4; ++it) {
            int c    = it * 256 + tid;
            int row  = c >> 3;
            int scol = ((c ^ (row & 7)) & 7) << 3;
            gload_lds16(A  + (size_t)(m0 + row) * K + k0 + scol, &sA[c * 8]);
            gload_lds16(Bt + (size_t)(n0 + row) * K + k0 + scol, &sB[c * 8]);
        }
        __syncthreads();

#pragma unroll
        for (int ks = 0; ks < 2; ++ks) {
            bfrag8 af[4], bfv[4];
#pragma unroll
            for (int mt = 0; mt < 4; ++mt) {
                int row = wm + mt * 16 + lrow;
                int G   = ks * 4 + quad;
                af[mt] = *(const bfrag8*)&sA[row * 64 + (((G ^ row) & 7) << 3)];
            }
#pragma unroll
            for (int nt = 0; nt < 4; ++nt) {
                int row = wn + nt * 16 + lrow;
                int G   = ks * 4 + quad;
                bfv[nt] = *(const bfrag8*)&sB[row * 64 + (((G ^ row) & 7) << 3)];
            }
            if (sel < 2) {
#pragma unroll
                for (int mt = 0; mt < 4; ++mt)
#pragma unroll
                    for (int nt = 0; nt < 4; ++nt)
                        acc[mt][nt] = __builtin_amdgcn_mfma_f32_16x16x32_bf16(
                            bfv[nt], af[mt], acc[mt][nt], 0, 0, 0);
            } else {
#pragma unroll
                for (int mt = 0; mt < 4; ++mt)
#pragma unroll
                    for (int nt = 0; nt < 4; ++nt)
                        acc[mt][nt] = __builtin_amdgcn_mfma_f32_16x16x32_bf16(
                            af[mt], bfv[nt], acc[mt][nt], 0, 0, 0);
            }
        }
        __syncthreads();
    }

    if (sel < 2) {
        ushort* C = (sel == 0) ? qb : kb;
        const float* bias = (sel == 0) ? bq : bk;
        const int colbase = n0 + wn;
#pragma unroll
        for (int nt = 0; nt < 4; ++nt) {
            int nb = (colbase + nt * 16 + quad * 4) & 1023;
            union { float4 v; float f[4]; } b4;
            b4.v = *(const float4*)(bias + nb);
#pragma unroll
            for (int mt = 0; mt < 4; ++mt) {
                int row = m0 + wm + mt * 16 + lrow;
                union { ushort u[4]; uint2 d; } t;
#pragma unroll
                for (int r = 0; r < 4; ++r) t.u[r] = f2bf(acc[mt][nt][r] + b4.f[r]);
                *(uint2*)(C + (size_t)row * DD + nb) = t.d;
            }
        }
    } else {
        const int colbase = n0 + wn;
#pragma unroll
        for (int nt = 0; nt < 4; ++nt) {
            int cc = (colbase + nt * 16 + lrow) & 1023;
            int h = cc >> 6, dh = cc & 63;
            float bb = bv[cc];
#pragma unroll
            for (int mt = 0; mt < 4; ++mt) {
                int row0 = m0 + wm + mt * 16 + (quad << 2);
                int b = row0 >> 12, s = row0 & 4095;
                union { ushort u[4]; uint2 d; } t;
#pragma unroll
                for (int r = 0; r < 4; ++r) t.u[r] = f2bf(acc[mt][nt][r] + bb);
                *(uint2*)(vT + (size_t)(((b * HH + h) * HDIM + dh)) * SS + s) = t.d;
            }
        }
    }
}

// ---------------------------------------------------------------------------
// Barrier-free MFMA flash attention. One wave per block; block = (qt, h, b).
// S^T = K·Q^T -> online softmax -> P via swizzled LDS -> O^T += V^T·P^T
// (V^T straight from global vT). No __syncthreads.
// ---------------------------------------------------------------------------
__global__ __launch_bounds__(64, 2) void attn_flash(
    const ushort* __restrict__ q, const ushort* __restrict__ k,
    const ushort* __restrict__ vT, ushort* __restrict__ out)
{
    __shared__ ushort sP[64 * 72];

    const int qt = blockIdx.x, h = blockIdx.y, b = blockIdx.z;
    const int lane = threadIdx.x;
    const int c16  = lane & 15;
    const int quad = lane >> 4;
    const float CC = 0.18033688011112042f;   // (1/sqrt(64)) * log2(e)

    bfrag8 qf[4][2];
    {
        const size_t qbase = ((size_t)b * SS + qt * 64) * DD + h * HDIM;
#pragma unroll
        for (int nt = 0; nt < 4; ++nt)
#pragma unroll
            for (int ks = 0; ks < 2; ++ks)
                qf[nt][ks] = *(const bfrag8*)(q + qbase +
                    (size_t)(nt * 16 + c16) * DD + ks * 32 + quad * 8);
    }

    floatx4 oacc[4][4];
#pragma unroll
    for (int i = 0; i < 4; ++i)
#pragma unroll
        for (int j = 0; j < 4; ++j)
            oacc[i][j] = (floatx4){0.f, 0.f, 0.f, 0.f};
    float mrow[4], lsum[4];
#pragma unroll
    for (int i = 0; i < 4; ++i) { mrow[i] = -1e30f; lsum[i] = 0.f; }

    const int st0 = (qt - 4 > 0) ? qt - 4 : 0;
    const int st1 = (qt + 4 < 63) ? qt + 4 : 63;
    const size_t kb_b  = (size_t)b * SS * DD + h * HDIM;
    const size_t vT_b  = (size_t)((b * HH + h) * HDIM) * SS;

    for (int st = st0; st <= st1; ++st) {
        const int dlt = st - qt;

        floatx4 sacc[4][4];
#pragma unroll
        for (int i = 0; i < 4; ++i)
#pragma unroll
            for (int j = 0; j < 4; ++j)
                sacc[i][j] = (floatx4){0.f, 0.f, 0.f, 0.f};
#pragma unroll
        for (int ks = 0; ks < 2; ++ks) {
            bfrag8 kf[4];
#pragma unroll
            for (int mt = 0; mt < 4; ++mt)
                kf[mt] = *(const bfrag8*)(k + kb_b +
                    (size_t)(st * 64 + mt * 16 + c16) * DD + ks * 32 + quad * 8);
#pragma unroll
            for (int mt = 0; mt < 4; ++mt)
#pragma unroll
                for (int nt = 0; nt < 4; ++nt)
                    sacc[mt][nt] = __builtin_amdgcn_mfma_f32_16x16x32_bf16(
                        kf[mt], qf[nt][ks], sacc[mt][nt], 0, 0, 0);
        }

        if (dlt == 4 || dlt == -4) {
#pragma unroll
            for (int mt = 0; mt < 4; ++mt)
#pragma unroll
                for (int nt = 0; nt < 4; ++nt)
#pragma unroll
                    for (int r = 0; r < 4; ++r) {
                        int kl = mt * 16 + quad * 4 + r;
                        int ql = nt * 16 + c16;
                        bool ok = (dlt < 0) ? (kl >= ql) : (kl <= ql);
                        if (!ok) sacc[mt][nt][r] = -1e30f;
                    }
        }

        float pm[4];
#pragma unroll
        for (int nt = 0; nt < 4; ++nt) {
            float a0 = fmaxf(fmaxf(sacc[0][nt][0], sacc[0][nt][1]),
                             fmaxf(sacc[0][nt][2], sacc[0][nt][3]));
            float a1 = fmaxf(fmaxf(sacc[1][nt][0], sacc[1][nt][1]),
                             fmaxf(sacc[1][nt][2], sacc[1][nt][3]));
            float a2 = fmaxf(fmaxf(sacc[2][nt][0], sacc[2][nt][1]),
                             fmaxf(sacc[2][nt][2], sacc[2][nt][3]));
            float a3 = fmaxf(fmaxf(sacc[3][nt][0], sacc[3][nt][1]),
                             fmaxf(sacc[3][nt][2], sacc[3][nt][3]));
            pm[nt] = fmaxf(fmaxf(a0, a1), fmaxf(a2, a3));
            pm[nt] = fmaxf(pm[nt], __shfl_xor(pm[nt], 16, 64));
            pm[nt] = fmaxf(pm[nt], __shfl_xor(pm[nt], 32, 64));
        }
        float al[4];
#pragma unroll
        for (int nt = 0; nt < 4; ++nt) {
            float mn = fmaxf(mrow[nt], pm[nt]);
            al[nt] = exp2f((mrow[nt] - mn) * CC);
            mrow[nt] = mn;
        }
        float ps[4] = {0.f, 0.f, 0.f, 0.f};
#pragma unroll
        for (int mt = 0; mt < 4; ++mt)
#pragma unroll
            for (int nt = 0; nt < 4; ++nt)
#pragma unroll
                for (int r = 0; r < 4; ++r) {
                    float p = exp2f((sacc[mt][nt][r] - mrow[nt]) * CC);
                    sacc[mt][nt][r] = p;
                    ps[nt] += p;
                }
#pragma unroll
        for (int nt = 0; nt < 4; ++nt) {
            ps[nt] += __shfl_xor(ps[nt], 16, 64);
            ps[nt] += __shfl_xor(ps[nt], 32, 64);
            lsum[nt] = lsum[nt] * al[nt] + ps[nt];
        }

#pragma unroll
        for (int mt = 0; mt < 4; ++mt)
#pragma unroll
            for (int nt = 0; nt < 4; ++nt) {
                int row = nt * 16 + c16;
                int g   = (2 * mt + (quad >> 1)) ^ (row & 3);
                union { ushort u[4]; uint2 d; } t;
#pragma unroll
                for (int r = 0; r < 4; ++r) t.u[r] = f2bf(sacc[mt][nt][r]);
                *(uint2*)&sP[row * 72 + g * 8 + (quad & 1) * 4] = t.d;
            }

#pragma unroll
        for (int dt = 0; dt < 4; ++dt)
#pragma unroll
            for (int nq = 0; nq < 4; ++nq)
#pragma unroll
                for (int r = 0; r < 4; ++r)
                    oacc[dt][nq][r] *= al[nq];

#pragma unroll
        for (int ks = 0; ks < 2; ++ks) {
            bfrag8 vf[4], pf[4];
#pragma unroll
            for (int dt = 0; dt < 4; ++dt)
                vf[dt] = *(const bfrag8*)(vT + vT_b +
                    (size_t)(dt * 16 + c16) * SS + st * 64 + ks * 32 + quad * 8);
#pragma unroll
            for (int nq = 0; nq < 4; ++nq) {
                int row = nq * 16 + c16;
                int g   = (4 * ks + quad) ^ (row & 3);
                pf[nq] = *(const bfrag8*)&sP[row * 72 + g * 8];
            }
#pragma unroll
            for (int dt = 0; dt < 4; ++dt)
#pragma unroll
                for (int nq = 0; nq < 4; ++nq)
                    oacc[dt][nq] = __builtin_amdgcn_mfma_f32_16x16x32_bf16(
                        vf[dt], pf[nq], oacc[dt][nq], 0, 0, 0);
        }
    }

#pragma unroll
    for (int nq = 0; nq < 4; ++nq) {
        float inv = 1.f / lsum[nq];
        size_t rbase = ((size_t)b * SS + qt * 64 + nq * 16 + c16) * DD + h * HDIM;
#pragma unroll
        for (int dt = 0; dt < 4; ++dt) {
            union { ushort u[4]; uint2 d; } t;
#pragma unroll
            for (int r = 0; r < 4; ++r) t.u[r] = f2bf(oacc[dt][nq][r] * inv);
            *(uint2*)(out + rbase + dt * 16 + quad * 4) = t.d;
        }
    }
}

// ---------------------------------------------------------------------------
// out = LayerNorm(a + res) * g + b    (one block per row of D=1024)
// ---------------------------------------------------------------------------
__device__ __forceinline__ float ldv(const float* p)  { return *p; }
__device__ __forceinline__ float ldv(const ushort* p) { return bf2f(*p); }
__device__ __forceinline__ void  stv(float* p, float v)  { *p = v; }
__device__ __forceinline__ void  stv(ushort* p, float v) { *p = f2bf(v); }

template <typename RT, typename OT>
__global__ __launch_bounds__(256) void add_ln(
    const ushort* __restrict__ a, const RT* __restrict__ res,
    const float* __restrict__ g, const float* __restrict__ bb,
    OT* __restrict__ out)
{
    const int row = blockIdx.x;
    const int tid = threadIdx.x;
    const size_t base = (size_t)row * DD + tid * 4;

    float x[4];
    float s1 = 0.f, s2 = 0.f;
#pragma unroll
    for (int e = 0; e < 4; ++e) {
        x[e] = bf2f(a[base + e]) + ldv(res + base + e);
        s1 += x[e];
        s2 += x[e] * x[e];
    }
#pragma unroll
    for (int off = 32; off > 0; off >>= 1) {
        s1 += __shfl_down(s1, off, 64);
        s2 += __shfl_down(s2, off, 64);
    }
    __shared__ float r1[4], r2[4];
    const int wave = tid >> 6, lane = tid & 63;
    if (lane == 0) { r1[wave] = s1; r2[wave] = s2; }
    __syncthreads();
    float t1 = r1[0] + r1[1] + r1[2] + r1[3];
    float t2 = r2[0] + r2[1] + r2[2] + r2[3];
    float mu  = t1 * (1.f / DD);
    float var = t2 * (1.f / DD) - mu * mu;
    float rs  = rsqrtf(var + 1e-5f);

#pragma unroll
    for (int e = 0; e < 4; ++e) {
        int col = tid * 4 + e;
        float y = (x[e] - mu) * rs * g[col] + bb[col];
        stv(out + base + e, y);
    }
}

// ---------------------------------------------------------------------------
extern "C" void kernel_launch(void* const* d_in, const int* in_sizes, int n_in,
                              void* d_out, int out_size, void* d_ws, size_t ws_size,
                              hipStream_t stream)
{
    (void)in_sizes; (void)n_in; (void)out_size; (void)ws_size;

    const float* x  = (const float*)d_in[0];
    const float* Wq = (const float*)d_in[1];
    const float* bq = (const float*)d_in[2];
    const float* Wk = (const float*)d_in[3];
    const float* bk = (const float*)d_in[4];
    const float* Wv = (const float*)d_in[5];
    const float* bv = (const float*)d_in[6];
    const float* Wo = (const float*)d_in[7];
    const float* bo = (const float*)d_in[8];
    const float* g1 = (const float*)d_in[9];
    const float* b1 = (const float*)d_in[10];
    const float* W1 = (const float*)d_in[11];
    const float* c1 = (const float*)d_in[12];
    const float* W2 = (const float*)d_in[13];
    const float* c2 = (const float*)d_in[14];
    const float* g2 = (const float*)d_in[15];
    const float* b2 = (const float*)d_in[16];
    float* outp = (float*)d_out;

    char* ws = (char*)d_ws;
    const size_t MB = 1024 * 1024;
    ushort* WqkvT = (ushort*)(ws);            // [  0,  6): Wq^T|Wk^T|Wv^T
    ushort* WoT = (ushort*)(ws + 6  * MB);    // [  6,  8)
    ushort* W1t = (ushort*)(ws + 8  * MB);    // [  8, 16)
    ushort* W2t = (ushort*)(ws + 16 * MB);    // [ 16, 24)
    ushort* xb  = (ushort*)(ws + 24 * MB);    // [ 24, 40)
    ushort* qb  = (ushort*)(ws + 40 * MB);    // [ 40, 56)
    ushort* kb  = (ushort*)(ws + 56 * MB);    // [ 56, 72)
    ushort* vT  = (ushort*)(ws + 72 * MB);    // [ 72, 88)  [b][h][64][4096]
    ushort* att = (ushort*)(ws + 88 * MB);    // [ 88,104)
    ushort* aproj = qb;
    ushort* hbuf  = att;
    ushort* m1  = (ushort*)(ws + 24 * MB);    // [ 24, 88)
    ushort* fbuf = (ushort*)(ws + 104 * MB);  // [104,120)

    dim3 blk(256, 1, 1);
    dim3 gD1((DD / 128) * (MROWS / 128), 1, 1);     // 512 blocks, 1D
    dim3 gQKV1((3 * DD / 128) * (MROWS / 128), 1, 1); // 1536 blocks
    dim3 gF1((FF / 128) * (MROWS / 128), 1, 1);     // 2048 blocks
    dim3 ga(SS / 64, HH, BB);
    dim3 gl(MROWS, 1, 1);

    hipLaunchKernelGGL(cvt_transpose_all, dim3(128, 32, 6), blk, 0, stream,
                       Wq, Wk, Wv, Wo, W1, W2, WqkvT, WoT, W1t, W2t);
    hipLaunchKernelGGL(cvt_f32_bf16, dim3(8192), blk, 0, stream, x, xb);

    hipLaunchKernelGGL(gemm_qkv, gQKV1, blk, 0, stream, xb, WqkvT, bq, bk, bv, qb, kb, vT);

    hipLaunchKernelGGL(attn_flash, ga, dim3(64, 1, 1), 0, stream, qb, kb, vT, att);

    hipLaunchKernelGGL(gemm_bt, gD1, blk, 0, stream, att, WoT, bo, aproj, MROWS, DD, DD, 0);
    hipLaunchKernelGGL((add_ln<float, ushort>), gl, blk, 0, stream, aproj, x, g1, b1, hbuf);

    hipLaunchKernelGGL(gemm_bt, gF1, blk, 0, stream, hbuf, W1t, c1, m1, MROWS, FF, DD, 1);
    hipLaunchKernelGGL(gemm_bt, gD1, blk, 0, stream, m1, W2t, c2, fbuf, MROWS, DD, FF, 0);
    hipLaunchKernelGGL((add_ln<ushort, float>), gl, blk, 0, stream, fbuf, hbuf, g2, b2, outp);
}